// Round 4
// baseline (2601.000 us; speedup 1.0000x reference)
//
#include <hip/hip_runtime.h>
#include <hip/hip_bf16.h>
#include <math.h>

#define Bd 128
#define Sd 256
#define Ad 8
#define Ed 300
#define Hd 300
#define EP 320
#define Pd 3
#define NCB 20   // blocks per GRU side
#define ROWS 48  // 3*16 gate rows per block

typedef __attribute__((ext_vector_type(8))) short bfrag;   // 8 bf16 (4 VGPRs)
typedef __attribute__((ext_vector_type(4))) float f32x4;   // MFMA acc

// ---- workspace layout (bytes) ----
#define OFF_LENS   0u           // int[128*4]
#define OFF_BARS   4096u        // int[8*64] : flag group (side*4+wave), slot cid
#define OFF_VA     8192u        // float[128*320]
#define OFF_VS     172032u      // float[128*320]
#define OFF_U      335872u      // float[128*320]
#define OFF_ATTN   499712u      // float[2*128*256]
#define OFF_ALPHA  761856u      // float[128*256]
#define OFF_C      892928u      // float[128*256]
#define OFF_HBUF   1024000u     // ushort[2*2*128*320]
#define OFF_PART   1351680u     // float[2*20*128*256]
#define OFF_W1B    6594560u     // ushort[320*320]
#define OFF_XEMB   6799360u     // ushort[2*256*128*320]
#define OFF_MEMW   48742400u    // ushort[128*256*320]
#define WS_NEEDED  69713920u

__device__ __forceinline__ unsigned short f2bf(float f) {
    __hip_bfloat16 h = __float2bfloat16(f);
    return *reinterpret_cast<unsigned short*>(&h);
}
__device__ __forceinline__ float bf2f(unsigned short u) {
    __hip_bfloat16 h = *reinterpret_cast<__hip_bfloat16*>(&u);
    return __bfloat162float(h);
}
__device__ __forceinline__ float sigm(float x) {
    return __builtin_amdgcn_rcpf(1.f + __expf(-x));
}
__device__ __forceinline__ float fast_tanh(float x) {
    x = fminf(fmaxf(x, -15.f), 15.f);
    float e = __expf(2.f * x);
    return (e - 1.f) * __builtin_amdgcn_rcpf(e + 1.f);
}

// coherent (LLC) 16B load of h as two 8B agent-scope relaxed atomics
__device__ __forceinline__ bfrag load_h16(const unsigned short* p) {
    union { unsigned long long q[2]; bfrag f; } u;
    unsigned long long* pp = (unsigned long long*)p;
    u.q[0] = __hip_atomic_load(pp,     __ATOMIC_RELAXED, __HIP_MEMORY_SCOPE_AGENT);
    u.q[1] = __hip_atomic_load(pp + 1, __ATOMIC_RELAXED, __HIP_MEMORY_SCOPE_AGENT);
    return u.f;
}

// ---------------- lengths ----------------
__global__ void k_lengths(const int* __restrict__ text, const int* __restrict__ aspect,
                          const int* __restrict__ xl, int* __restrict__ lens) {
    int b = blockIdx.x;
    __shared__ int red[3];
    if (threadIdx.x < 3) red[threadIdx.x] = 0;
    __syncthreads();
    int t = threadIdx.x;
    if (t < Sd) {
        if (text[b*Sd + t] != 0) atomicAdd(&red[0], 1);
        if (xl[b*Sd + t]  != 0) atomicAdd(&red[2], 1);
    }
    if (t < Ad) { if (aspect[b*Ad + t] != 0) atomicAdd(&red[1], 1); }
    __syncthreads();
    if (t < 3) lens[b*4 + t] = red[t];
}

// ---------------- v_a ----------------
__global__ void k_va(const float* __restrict__ embed, const int* __restrict__ aspect,
                     const int* __restrict__ lens, float* __restrict__ va) {
    int b = blockIdx.x;
    __shared__ int aidx[Ad];
    if (threadIdx.x < Ad) aidx[threadIdx.x] = aspect[b*Ad + threadIdx.x];
    __syncthreads();
    float inv = 1.0f / (float)lens[b*4+1];
    for (int e = threadIdx.x; e < EP; e += blockDim.x) {
        float s = 0.f;
        if (e < Ed) {
            for (int a = 0; a < Ad; ++a) s += embed[(size_t)aidx[a]*Ed + e];
        }
        va[b*EP + e] = s * inv;
    }
}

// ---------------- gather embeddings for GRU inputs (bf16, [side][t][b][EP]) ----------------
__global__ void k_xemb(const float* __restrict__ embed, const int* __restrict__ xl,
                       const int* __restrict__ xr, unsigned short* __restrict__ xemb) {
    int side = blockIdx.x >> 8;
    int t = blockIdx.x & 255;
    const int* xs = side ? xr : xl;
    __shared__ int rows_s[Bd];
    if (threadIdx.x < Bd) rows_s[threadIdx.x] = xs[threadIdx.x*Sd + t];
    __syncthreads();
    unsigned short* dst = xemb + ((size_t)(side*Sd + t) * Bd) * EP;
    for (int idx = threadIdx.x; idx < Bd*EP; idx += blockDim.x) {
        int b = idx / EP, k = idx - b*EP;
        float v = (k < Ed) ? embed[(size_t)rows_s[b]*Ed + k] : 0.f;
        dst[idx] = f2bf(v);
    }
}

// ---------------- w1 mem-part -> bf16 padded [320][320] ----------------
__global__ void k_w1conv(const float* __restrict__ w1, unsigned short* __restrict__ w1b) {
    int idx = blockIdx.x*256 + threadIdx.x;
    if (idx >= EP*EP) return;
    int e = idx / EP, k = idx - e*EP;
    float v = (e < Ed && k < Ed) ? w1[(size_t)e*900 + k] : 0.f;
    w1b[idx] = f2bf(v);
}

// ---------------- persistent GRU (both sides) ----------------
// Sync fabric v3 (decontended):
//  - producer: per-(side,wave) FLAG SLOT per block -> plain relaxed store, no RMW
//  - consumer: ONE coalesced vector load polls all 20 flags (lanes 0..19), __all()
//  - part stores issued AFTER the flag store (drain off the critical path)
//  - x fragments register-double-buffered; h via agent-scope relaxed atomics
__global__ __launch_bounds__(256, 1) void k_gru(
        const float* __restrict__ wih_l, const float* __restrict__ whh_l,
        const float* __restrict__ bih_l, const float* __restrict__ bhh_l,
        const float* __restrict__ wih_r, const float* __restrict__ whh_r,
        const float* __restrict__ bih_r, const float* __restrict__ bhh_r,
        const float* __restrict__ wml, const float* __restrict__ wmr,
        const unsigned short* __restrict__ xemb,
        unsigned short* __restrict__ hbuf,
        float* __restrict__ part, int* __restrict__ bars) {
    // side-parity remap: side0 -> even blockIdx (even XCDs), side1 -> odd
    int side = blockIdx.x & 1;
    int cid  = blockIdx.x >> 1;
    int u0 = cid * 16;
    const float* wih = side ? wih_r : wih_l;
    const float* whh = side ? whh_r : whh_l;
    const float* bih = side ? bih_r : bih_l;
    const float* bhh = side ? bhh_r : bhh_l;
    const float* wmv = side ? wmr : wml;

    __shared__ __align__(16) unsigned short wih_s[ROWS*328];
    __shared__ __align__(16) unsigned short whh_s[ROWS*328];
    __shared__ float bih_sh[ROWS], bhh_sh[ROWS], wml_sh[16];

    for (int idx = threadIdx.x; idx < ROWS*328; idx += 256) {
        int lr = idx / 328, k = idx - lr*328;
        int g = lr >> 4, ulw = lr & 15, u = u0 + ulw;
        float vi = 0.f, vh = 0.f;
        if (u < Hd && k < Ed) {
            int grow = g*Hd + u;
            vi = wih[(size_t)grow*Ed + k];
            vh = whh[(size_t)grow*Hd + k];
        }
        wih_s[idx] = f2bf(vi);
        whh_s[idx] = f2bf(vh);
    }
    if (threadIdx.x < ROWS) {
        int g = threadIdx.x >> 4, ulw = threadIdx.x & 15, u = u0 + ulw;
        bih_sh[threadIdx.x] = (u < Hd) ? bih[g*Hd + u] : 0.f;
        bhh_sh[threadIdx.x] = (u < Hd) ? bhh[g*Hd + u] : 0.f;
    }
    if (threadIdx.x < 16) {
        int u = u0 + threadIdx.x;
        wml_sh[threadIdx.x] = (u < Hd) ? wmv[u] : 0.f;
    }
    __syncthreads();

    int wave = threadIdx.x >> 6;
    int lane = threadIdx.x & 63;
    int rowbase = wave * 32;
    int ul = lane & 15;
    int lq = lane >> 4;

    float hreg[2][4] = {{0.f,0.f,0.f,0.f},{0.f,0.f,0.f,0.f}};
    unsigned short* hb = hbuf + (size_t)side * 2 * Bd * EP;
    int* flg = bars + (side*4 + wave)*64;   // flag slots: flg[cid] = ready generation
    const f32x4 zero4 = {0.f, 0.f, 0.f, 0.f};
    int pollslot = (lane < NCB) ? lane : (NCB-1);

    // preload x fragments for t=0
    bfrag xcur[2][10];
    {
        const unsigned short* xg = xemb + ((size_t)(side*Sd + 0)*Bd)*EP;
        #pragma unroll
        for (int m = 0; m < 2; ++m) {
            int row = rowbase + m*16 + ul;
            #pragma unroll
            for (int kp = 0; kp < 10; ++kp)
                xcur[m][kp] = *(const bfrag*)(xg + (size_t)row*EP + kp*32 + lq*8);
        }
    }

    #pragma unroll 1
    for (int t = 0; t < Sd; ++t) {
        const unsigned short* hg = hb + (size_t)(t & 1)*Bd*EP;
        unsigned short* hnx = hb + (size_t)((t+1) & 1)*Bd*EP;

        f32x4 agi[2][3], agh[2][3];
        #pragma unroll
        for (int m = 0; m < 2; ++m)
            #pragma unroll
            for (int n = 0; n < 3; ++n) { agi[m][n] = zero4; agh[m][n] = zero4; }

        // ---- phase 1: gi = x_t @ wih^T  (pure register A-operands) ----
        #pragma unroll
        for (int kp = 0; kp < 10; ++kp) {
            int koff = kp*32 + lq*8;
            bfrag bi[3];
            #pragma unroll
            for (int n = 0; n < 3; ++n)
                bi[n] = *(const bfrag*)(wih_s + (n*16 + ul)*328 + koff);
            #pragma unroll
            for (int m = 0; m < 2; ++m)
                #pragma unroll
                for (int n = 0; n < 3; ++n)
                    agi[m][n] = __builtin_amdgcn_mfma_f32_16x16x32_bf16(xcur[m][kp], bi[n], agi[m][n], 0, 0, 0);
        }

        // ---- issue x prefetch for t+1 (completes during phase2/epilogue) ----
        {
            int tn = (t + 1 < Sd) ? (t + 1) : (Sd - 1);
            const unsigned short* xg = xemb + ((size_t)(side*Sd + tn)*Bd)*EP;
            #pragma unroll
            for (int m = 0; m < 2; ++m) {
                int row = rowbase + m*16 + ul;
                #pragma unroll
                for (int kp = 0; kp < 10; ++kp)
                    xcur[m][kp] = *(const bfrag*)(xg + (size_t)row*EP + kp*32 + lq*8);
            }
        }

        // ---- spin: one coalesced poll load over all NCB flags, __all >= t ----
        if (t > 0) {
            while (true) {
                int v = __hip_atomic_load(flg + pollslot, __ATOMIC_RELAXED, __HIP_MEMORY_SCOPE_AGENT);
                if (__all(v >= t)) break;
                __builtin_amdgcn_s_sleep(1);
            }
        }
        asm volatile("" ::: "memory");

        // ---- phase 2: gh = h @ whh^T  (coherent h loads) ----
        #pragma unroll
        for (int kp = 0; kp < 10; ++kp) {
            int koff = kp*32 + lq*8;
            bfrag ah[2], bh[3];
            #pragma unroll
            for (int m = 0; m < 2; ++m) {
                int row = rowbase + m*16 + ul;
                ah[m] = load_h16(hg + (size_t)row*EP + koff);
            }
            #pragma unroll
            for (int n = 0; n < 3; ++n)
                bh[n] = *(const bfrag*)(whh_s + (n*16 + ul)*328 + koff);
            #pragma unroll
            for (int m = 0; m < 2; ++m)
                #pragma unroll
                for (int n = 0; n < 3; ++n)
                    agh[m][n] = __builtin_amdgcn_mfma_f32_16x16x32_bf16(ah[m], bh[n], agh[m][n], 0, 0, 0);
        }

        // ---- epilogue: gates, h update, coherent h store ----
        #pragma unroll
        for (int m = 0; m < 2; ++m) {
            #pragma unroll
            for (int i = 0; i < 4; ++i) {
                float gr = agi[m][0][i] + bih_sh[ul]    + agh[m][0][i] + bhh_sh[ul];
                float gz = agi[m][1][i] + bih_sh[16+ul] + agh[m][1][i] + bhh_sh[16+ul];
                float gn = agi[m][2][i] + bih_sh[32+ul];
                float hn_g = agh[m][2][i] + bhh_sh[32+ul];
                float r = sigm(gr);
                float z = sigm(gz);
                float nn = fast_tanh(gn + r*hn_g);
                float hv = (1.f - z)*nn + z*hreg[m][i];
                hreg[m][i] = hv;
                int brow = rowbase + m*16 + lq*4 + i;

                float hv2 = __shfl_xor(hv, 1, 64);
                unsigned int pk = ((unsigned)f2bf(hv2) << 16) | (unsigned)f2bf(hv);
                if ((ul & 1) == 0)
                    __hip_atomic_store((unsigned int*)(hnx + (size_t)brow*EP + u0 + ul), pk,
                                       __ATOMIC_RELAXED, __HIP_MEMORY_SCOPE_AGENT);
            }
        }

        // drain h stores to the coherent point, then publish readiness (no RMW)
        asm volatile("s_waitcnt vmcnt(0)" ::: "memory");
        if (t < Sd-1 && lane == 0)
            __hip_atomic_store(flg + cid, t+1, __ATOMIC_RELAXED, __HIP_MEMORY_SCOPE_AGENT);

        // ---- attn partials (off critical path; drain covered by next step) ----
        #pragma unroll
        for (int m = 0; m < 2; ++m) {
            #pragma unroll
            for (int i = 0; i < 4; ++i) {
                int brow = rowbase + m*16 + lq*4 + i;
                float pv = hreg[m][i] * wml_sh[ul];
                pv += __shfl_xor(pv, 1, 64);
                pv += __shfl_xor(pv, 2, 64);
                pv += __shfl_xor(pv, 4, 64);
                pv += __shfl_xor(pv, 8, 64);
                if (ul == 0)
                    part[((size_t)(side*NCB + cid)*Bd + brow)*Sd + t] = pv;
            }
        }
    }
}

// ---------------- reduce attn partials ----------------
__global__ void k_attn(const float* __restrict__ part, const float* __restrict__ bml,
                       const float* __restrict__ bmr, float* __restrict__ attn) {
    int side = blockIdx.x >> 7;
    int b = blockIdx.x & 127;
    int t = threadIdx.x;
    float s = 0.f;
    for (int c = 0; c < NCB; ++c)
        s += part[((size_t)(side*NCB + c)*Bd + b)*Sd + t];
    float bias = side ? bmr[0] : bml[0];
    attn[(size_t)(side*Bd + b)*Sd + t] = sigm(s + bias) + 0.5f;
}

// ---------------- position weights + weighted memory + v_s ----------------
__global__ void k_wmem(const float* __restrict__ embed, const int* __restrict__ text,
                       const float* __restrict__ attn, const int* __restrict__ lens,
                       unsigned short* __restrict__ memw, float* __restrict__ vs) {
    int b = blockIdx.x;
    __shared__ float w_sh[Sd];
    __shared__ int text_s[Sd];
    int memlen = lens[b*4+0], asplen = lens[b*4+1], leftlen = lens[b*4+2];
    int a_start = leftlen - asplen, a_end = leftlen;
    const float* attl = attn + (size_t)b*Sd;
    const float* attr = attn + (size_t)(Bd + b)*Sd;
    if (threadIdx.x < Sd) {
        int i = threadIdx.x;
        int irr = a_end - 1 - i; irr = irr < 0 ? 0 : (irr > Sd-1 ? Sd-1 : irr);
        int ils = i - a_start;   ils = ils < 0 ? 0 : (ils > Sd-1 ? Sd-1 : ils);
        float arr_ = attr[irr], als = attl[ils];
        float w = (i < a_start) ? arr_ : ((i < a_end) ? 0.5f*(arr_+als) : als);
        if (i >= memlen) w = 1.0f;
        w_sh[i] = w;
        text_s[i] = text[b*Sd + i];
    }
    __syncthreads();
    int e = threadIdx.x;
    float acc = 0.f;
    float invm = 1.0f/(float)lens[b*4+0];
    for (int s = 0; s < Sd; ++s) {
        float v = (e < Ed) ? embed[(size_t)text_s[s]*Ed + e] : 0.f;
        float mw = v * w_sh[s];
        memw[((size_t)b*Sd + s)*EP + e] = f2bf(mw);
        acc += mw;
    }
    vs[b*EP + e] = acc * invm;
}

// ---------------- per-batch u = b1 + va@W1a^T + vs@W1s^T ----------------
__global__ void k_u(const float* __restrict__ w1, const float* __restrict__ b1,
                    const float* __restrict__ va, const float* __restrict__ vs,
                    float* __restrict__ u) {
    int b = blockIdx.x;
    __shared__ float va_s[Ed], vs_s[Ed];
    for (int k = threadIdx.x; k < Ed; k += blockDim.x) {
        va_s[k] = va[b*EP+k];
        vs_s[k] = vs[b*EP+k];
    }
    __syncthreads();
    int e = threadIdx.x;
    if (e >= EP) return;
    float acc = 0.f;
    if (e < Ed) {
        acc = b1[e];
        const float* r = w1 + (size_t)e*900;
        for (int k = 0; k < Ed; ++k) acc += va_s[k]*r[300+k];
        for (int k = 0; k < Ed; ++k) acc += vs_s[k]*r[600+k];
    }
    u[b*EP + e] = acc;
}

// ---------------- c[b,s] = w2 . tanh(memw@W1m^T + u)  (MFMA) ----------------
__global__ __launch_bounds__(256) void k_c(const unsigned short* __restrict__ memw,
                   const unsigned short* __restrict__ w1b,
                   const float* __restrict__ u, const float* __restrict__ w2,
                   float* __restrict__ cout) {
    int b = blockIdx.x >> 2;
    int s0 = (blockIdx.x & 3) * 64;
    __shared__ __align__(16) unsigned short A_s[64*328];
    __shared__ __align__(16) unsigned short Bp_s[EP*32];
    __shared__ float u_s[EP], w2_s[EP];
    for (int i = threadIdx.x; i < EP; i += 256) {
        u_s[i] = u[b*EP + i];
        w2_s[i] = (i < Ed) ? w2[i] : 0.f;
    }
    const unsigned short* Ag = memw + ((size_t)b*Sd + s0)*EP;
    for (int c8 = threadIdx.x; c8 < 64*40; c8 += 256) {
        int r = c8 / 40, kk = (c8 - r*40)*8;
        *(bfrag*)(A_s + r*328 + kk) = *(const bfrag*)(Ag + (size_t)r*EP + kk);
    }

    int wave = threadIdx.x >> 6, lane = threadIdx.x & 63;
    int ul = lane & 15, lq = lane >> 4;
    const f32x4 zero4 = {0.f,0.f,0.f,0.f};
    f32x4 acc[20];
    #pragma unroll
    for (int n = 0; n < 20; ++n) acc[n] = zero4;

    for (int kp = 0; kp < 10; ++kp) {
        __syncthreads();
        for (int c8 = threadIdx.x; c8 < EP*4; c8 += 256) {
            int e = c8 >> 2, kk = (c8 & 3)*8;
            *(bfrag*)(Bp_s + e*32 + kk) = *(const bfrag*)(w1b + (size_t)e*EP + kp*32 + kk);
        }
        __syncthreads();
        bfrag a = *(const bfrag*)(A_s + (wave*16 + ul)*328 + kp*32 + lq*8);
        #pragma unroll
        for (int n = 0; n < 20; ++n) {
            bfrag bb = *(const bfrag*)(Bp_s + (n*16 + ul)*32 + lq*8);
            acc[n] = __builtin_amdgcn_mfma_f32_16x16x32_bf16(a, bb, acc[n], 0, 0, 0);
        }
    }
    float cs[4] = {0.f,0.f,0.f,0.f};
    #pragma unroll
    for (int n = 0; n < 20; ++n) {
        int e = n*16 + ul;
        #pragma unroll
        for (int i = 0; i < 4; ++i)
            cs[i] += w2_s[e] * fast_tanh(acc[n][i] + u_s[e]);
    }
    #pragma unroll
    for (int i = 0; i < 4; ++i) {
        float v = cs[i];
        v += __shfl_xor(v, 1, 64); v += __shfl_xor(v, 2, 64);
        v += __shfl_xor(v, 4, 64); v += __shfl_xor(v, 8, 64);
        if (ul == 0) cout[(size_t)b*Sd + s0 + wave*16 + lq*4 + i] = v;
    }
}

// ---------------- softmax over s ----------------
__global__ void k_alpha(const float* __restrict__ cin, float* __restrict__ alpha) {
    int b = blockIdx.x;
    int t = threadIdx.x;
    __shared__ float buf[Sd];
    float v = cin[(size_t)b*Sd + t];
    buf[t] = v; __syncthreads();
    for (int s2 = 128; s2 > 0; s2 >>= 1) {
        if (t < s2) buf[t] = fmaxf(buf[t], buf[t+s2]);
        __syncthreads();
    }
    float mx = buf[0];
    __syncthreads();
    float ex = __expf(v - mx);
    buf[t] = ex; __syncthreads();
    for (int s2 = 128; s2 > 0; s2 >>= 1) {
        if (t < s2) buf[t] += buf[t+s2];
        __syncthreads();
    }
    alpha[(size_t)b*Sd + t] = ex / buf[0];
}

// ---------------- v_ts, v_ns, v_ms, logits, softmax ----------------
__global__ void k_final(const unsigned short* __restrict__ memw, const float* __restrict__ alpha,
                        const float* __restrict__ vs, const float* __restrict__ wm,
                        const float* __restrict__ bm, const float* __restrict__ wd,
                        const float* __restrict__ bd, float* __restrict__ out) {
    int b = blockIdx.x;
    __shared__ float al_s[Sd];
    __shared__ float vns_s[Ed];
    __shared__ float vms_s[Ed];
    __shared__ float lg_s[Pd];
    if (threadIdx.x < Sd) al_s[threadIdx.x] = alpha[(size_t)b*Sd + threadIdx.x];
    __syncthreads();
    int e = threadIdx.x;
    if (e < Ed) {
        float acc = 0.f;
        const unsigned short* mp = memw + (size_t)b*Sd*EP + e;
        for (int s = 0; s < Sd; ++s) acc += bf2f(mp[(size_t)s*EP]) * al_s[s];
        vns_s[e] = acc + vs[b*EP + e];
    }
    __syncthreads();
    if (e < Ed) {
        float acc = bm[e];
        const float* r = wm + (size_t)e*Ed;
        for (int k = 0; k < Ed; ++k) acc += vns_s[k]*r[k];
        vms_s[e] = fast_tanh(acc);
    }
    __syncthreads();
    if (e < Pd) {
        float acc = bd[e];
        const float* r = wd + (size_t)e*Ed;
        for (int k = 0; k < Ed; ++k) acc += vms_s[k]*r[k];
        lg_s[e] = acc;
    }
    __syncthreads();
    if (e < Pd) {
        float m = fmaxf(lg_s[0], fmaxf(lg_s[1], lg_s[2]));
        float den = __expf(lg_s[0]-m)+__expf(lg_s[1]-m)+__expf(lg_s[2]-m);
        out[b*Pd + e] = __expf(lg_s[e]-m)/den;
    }
}

extern "C" void kernel_launch(void* const* d_in, const int* in_sizes, int n_in,
                              void* d_out, int out_size, void* d_ws, size_t ws_size,
                              hipStream_t stream) {
    const float* embed = (const float*)d_in[0];
    const float* w1    = (const float*)d_in[1];
    const float* b1    = (const float*)d_in[2];
    const float* w2    = (const float*)d_in[3];
    const float* wm    = (const float*)d_in[4];
    const float* bm    = (const float*)d_in[5];
    const float* wd    = (const float*)d_in[6];
    const float* bd    = (const float*)d_in[7];
    const float* wih_l = (const float*)d_in[8];
    const float* whh_l = (const float*)d_in[9];
    const float* bih_l = (const float*)d_in[10];
    const float* bhh_l = (const float*)d_in[11];
    const float* wih_r = (const float*)d_in[12];
    const float* whh_r = (const float*)d_in[13];
    const float* bih_r = (const float*)d_in[14];
    const float* bhh_r = (const float*)d_in[15];
    const float* wml   = (const float*)d_in[16];
    const float* bml   = (const float*)d_in[17];
    const float* wmr   = (const float*)d_in[18];
    const float* bmr   = (const float*)d_in[19];
    const int* text    = (const int*)d_in[20];
    const int* aspect  = (const int*)d_in[21];
    const int* xl      = (const int*)d_in[22];
    const int* xr      = (const int*)d_in[23];

    if (ws_size < (size_t)WS_NEEDED) return;
    char* ws = (char*)d_ws;
    int* lens            = (int*)(ws + OFF_LENS);
    int* bars            = (int*)(ws + OFF_BARS);
    float* va            = (float*)(ws + OFF_VA);
    float* vs            = (float*)(ws + OFF_VS);
    float* u             = (float*)(ws + OFF_U);
    float* attn          = (float*)(ws + OFF_ATTN);
    float* alpha         = (float*)(ws + OFF_ALPHA);
    float* c             = (float*)(ws + OFF_C);
    unsigned short* hbuf = (unsigned short*)(ws + OFF_HBUF);
    float* part          = (float*)(ws + OFF_PART);
    unsigned short* w1b  = (unsigned short*)(ws + OFF_W1B);
    unsigned short* xemb = (unsigned short*)(ws + OFF_XEMB);
    unsigned short* memw = (unsigned short*)(ws + OFF_MEMW);

    hipMemsetAsync(ws + OFF_BARS, 0, 4096, stream);
    hipMemsetAsync(ws + OFF_HBUF, 0, 327680, stream);

    k_lengths<<<128, 256, 0, stream>>>(text, aspect, xl, lens);
    k_va     <<<128, 320, 0, stream>>>(embed, aspect, lens, va);
    k_xemb   <<<512, 256, 0, stream>>>(embed, xl, xr, xemb);
    k_w1conv <<<400, 256, 0, stream>>>(w1, w1b);
    k_gru    <<<2*NCB, 256, 0, stream>>>(wih_l, whh_l, bih_l, bhh_l,
                                         wih_r, whh_r, bih_r, bhh_r,
                                         wml, wmr, xemb, hbuf, part, bars);
    k_attn   <<<256, 256, 0, stream>>>(part, bml, bmr, attn);
    k_wmem   <<<128, 320, 0, stream>>>(embed, text, attn, lens, memw, vs);
    k_u      <<<128, 320, 0, stream>>>(w1, b1, va, vs, u);
    k_c      <<<512, 256, 0, stream>>>(memw, w1b, u, w2, c);
    k_alpha  <<<128, 256, 0, stream>>>(c, alpha);
    k_final  <<<128, 320, 0, stream>>>(memw, alpha, vs, wm, bm, wd, bd, (float*)d_out);
}

// Round 5
// 2056.134 us; speedup vs baseline: 1.2650x; 1.2650x over previous
//
#include <hip/hip_runtime.h>
#include <hip/hip_bf16.h>
#include <math.h>

#define Bd 128
#define Sd 256
#define Ad 8
#define Ed 300
#define Hd 300
#define EP 320
#define Pd 3
#define NCB 20   // blocks per GRU side
#define ROWS 48  // 3*16 gate rows per block

typedef __attribute__((ext_vector_type(8))) short bfrag;   // 8 bf16 (4 VGPRs)
typedef __attribute__((ext_vector_type(4))) float f32x4;   // MFMA acc

// ---- workspace layout (bytes) ----
#define OFF_LENS   0u           // int[128*4]
#define OFF_BARS   4096u        // int[2*64] : per-side flag group, slot cid
#define OFF_VA     8192u        // float[128*320]
#define OFF_VS     172032u      // float[128*320]
#define OFF_U      335872u      // float[128*320]
#define OFF_ATTN   499712u      // float[2*128*256]
#define OFF_ALPHA  761856u      // float[128*256]
#define OFF_C      892928u      // float[128*256]
#define OFF_HBUF   1024000u     // ushort[2 side][2 parity][20 cb][128 row][16 u]
#define OFF_PART   1351680u     // float[2*20*128*256]
#define OFF_W1B    6594560u     // ushort[320*320]
#define OFF_XEMB   6799360u     // ushort[2*256*128*320]
#define OFF_MEMW   48742400u    // ushort[128*256*320]
#define WS_NEEDED  69713920u

#define HREG 40960              // ushorts per (side,parity) h region

__device__ __forceinline__ unsigned short f2bf(float f) {
    __hip_bfloat16 h = __float2bfloat16(f);
    return *reinterpret_cast<unsigned short*>(&h);
}
__device__ __forceinline__ float bf2f(unsigned short u) {
    __hip_bfloat16 h = *reinterpret_cast<__hip_bfloat16*>(&u);
    return __bfloat162float(h);
}
__device__ __forceinline__ float sigm(float x) {
    return __builtin_amdgcn_rcpf(1.f + __expf(-x));
}
__device__ __forceinline__ float fast_tanh(float x) {
    x = fminf(fmaxf(x, -15.f), 15.f);
    float e = __expf(2.f * x);
    return (e - 1.f) * __builtin_amdgcn_rcpf(e + 1.f);
}

// ---------------- lengths ----------------
__global__ void k_lengths(const int* __restrict__ text, const int* __restrict__ aspect,
                          const int* __restrict__ xl, int* __restrict__ lens) {
    int b = blockIdx.x;
    __shared__ int red[3];
    if (threadIdx.x < 3) red[threadIdx.x] = 0;
    __syncthreads();
    int t = threadIdx.x;
    if (t < Sd) {
        if (text[b*Sd + t] != 0) atomicAdd(&red[0], 1);
        if (xl[b*Sd + t]  != 0) atomicAdd(&red[2], 1);
    }
    if (t < Ad) { if (aspect[b*Ad + t] != 0) atomicAdd(&red[1], 1); }
    __syncthreads();
    if (t < 3) lens[b*4 + t] = red[t];
}

// ---------------- v_a ----------------
__global__ void k_va(const float* __restrict__ embed, const int* __restrict__ aspect,
                     const int* __restrict__ lens, float* __restrict__ va) {
    int b = blockIdx.x;
    __shared__ int aidx[Ad];
    if (threadIdx.x < Ad) aidx[threadIdx.x] = aspect[b*Ad + threadIdx.x];
    __syncthreads();
    float inv = 1.0f / (float)lens[b*4+1];
    for (int e = threadIdx.x; e < EP; e += blockDim.x) {
        float s = 0.f;
        if (e < Ed) {
            for (int a = 0; a < Ad; ++a) s += embed[(size_t)aidx[a]*Ed + e];
        }
        va[b*EP + e] = s * inv;
    }
}

// ---------------- gather embeddings for GRU inputs (bf16, [side][t][b][EP]) ----------------
__global__ void k_xemb(const float* __restrict__ embed, const int* __restrict__ xl,
                       const int* __restrict__ xr, unsigned short* __restrict__ xemb) {
    int side = blockIdx.x >> 8;
    int t = blockIdx.x & 255;
    const int* xs = side ? xr : xl;
    __shared__ int rows_s[Bd];
    if (threadIdx.x < Bd) rows_s[threadIdx.x] = xs[threadIdx.x*Sd + t];
    __syncthreads();
    unsigned short* dst = xemb + ((size_t)(side*Sd + t) * Bd) * EP;
    for (int idx = threadIdx.x; idx < Bd*EP; idx += blockDim.x) {
        int b = idx / EP, k = idx - b*EP;
        float v = (k < Ed) ? embed[(size_t)rows_s[b]*Ed + k] : 0.f;
        dst[idx] = f2bf(v);
    }
}

// ---------------- w1 mem-part -> bf16 padded [320][320] ----------------
__global__ void k_w1conv(const float* __restrict__ w1, unsigned short* __restrict__ w1b) {
    int idx = blockIdx.x*256 + threadIdx.x;
    if (idx >= EP*EP) return;
    int e = idx / EP, k = idx - e*EP;
    float v = (e < Ed && k < Ed) ? w1[(size_t)e*900 + k] : 0.f;
    w1b[idx] = f2bf(v);
}

// ---------------- persistent GRU (both sides) ----------------
// v4: h exchange fully COALESCED.
//  - hbuf column-blocked [cb][row][u16]: each block's output contiguous (4KB)
//  - h staged global->LDS linearly (64B line-granular at LLC), phase2 reads LDS
//  - new h gathered in hn_s (4KB LDS) then stored as consecutive 8B atomics
//  - per-side flag group doubles as buffer-release token
__global__ __launch_bounds__(256, 1) void k_gru(
        const float* __restrict__ wih_l, const float* __restrict__ whh_l,
        const float* __restrict__ bih_l, const float* __restrict__ bhh_l,
        const float* __restrict__ wih_r, const float* __restrict__ whh_r,
        const float* __restrict__ bih_r, const float* __restrict__ bhh_r,
        const float* __restrict__ wml, const float* __restrict__ wmr,
        const unsigned short* __restrict__ xemb,
        unsigned short* __restrict__ hbuf,
        float* __restrict__ part, int* __restrict__ bars) {
    // side-parity remap: side0 -> even blockIdx (even XCDs), side1 -> odd
    int side = blockIdx.x & 1;
    int cid  = blockIdx.x >> 1;
    int u0 = cid * 16;
    int tid = threadIdx.x;
    const float* wih = side ? wih_r : wih_l;
    const float* whh = side ? whh_r : whh_l;
    const float* bih = side ? bih_r : bih_l;
    const float* bhh = side ? bhh_r : bhh_l;
    const float* wmv = side ? wmr : wml;

    __shared__ __align__(16) unsigned short wih_s[ROWS*328];
    __shared__ __align__(16) unsigned short whh_s[ROWS*328];
    __shared__ __align__(16) unsigned short h_s[HREG];        // [20 cb][128 row][16 u]
    __shared__ __align__(16) unsigned short hn_s[Bd*16];      // [128 row][16 u]
    __shared__ float bih_sh[ROWS], bhh_sh[ROWS], wml_sh[16];

    for (int idx = tid; idx < ROWS*328; idx += 256) {
        int lr = idx / 328, k = idx - lr*328;
        int g = lr >> 4, ulw = lr & 15, u = u0 + ulw;
        float vi = 0.f, vh = 0.f;
        if (u < Hd && k < Ed) {
            int grow = g*Hd + u;
            vi = wih[(size_t)grow*Ed + k];
            vh = whh[(size_t)grow*Hd + k];
        }
        wih_s[idx] = f2bf(vi);
        whh_s[idx] = f2bf(vh);
    }
    if (tid < ROWS) {
        int g = tid >> 4, ulw = tid & 15, u = u0 + ulw;
        bih_sh[tid] = (u < Hd) ? bih[g*Hd + u] : 0.f;
        bhh_sh[tid] = (u < Hd) ? bhh[g*Hd + u] : 0.f;
    }
    if (tid < 16) {
        int u = u0 + tid;
        wml_sh[tid] = (u < Hd) ? wmv[u] : 0.f;
    }
    __syncthreads();

    int wave = tid >> 6;
    int lane = tid & 63;
    int rowbase = wave * 32;
    int ul = lane & 15;
    int lq = lane >> 4;

    float hreg[2][4] = {{0.f,0.f,0.f,0.f},{0.f,0.f,0.f,0.f}};
    unsigned short* hb = hbuf + (size_t)side * 2 * HREG;   // [parity][HREG]
    int* flg = bars + side*64;                             // flg[cid] = ready gen
    const f32x4 zero4 = {0.f, 0.f, 0.f, 0.f};
    int pollslot = (lane < NCB) ? lane : (NCB-1);

    // preload x fragments for t=0
    bfrag xcur[2][10];
    {
        const unsigned short* xg = xemb + ((size_t)(side*Sd + 0)*Bd)*EP;
        #pragma unroll
        for (int m = 0; m < 2; ++m) {
            int row = rowbase + m*16 + ul;
            #pragma unroll
            for (int kp = 0; kp < 10; ++kp)
                xcur[m][kp] = *(const bfrag*)(xg + (size_t)row*EP + kp*32 + lq*8);
        }
    }

    #pragma unroll 1
    for (int t = 0; t < Sd; ++t) {
        const unsigned long long* hg8 =
            (const unsigned long long*)(hb + (size_t)(t & 1)*HREG);
        unsigned long long* hn8 =
            (unsigned long long*)(hb + (size_t)((t+1) & 1)*HREG) + (size_t)cid*512;

        f32x4 agi[2][3], agh[2][3];
        #pragma unroll
        for (int m = 0; m < 2; ++m)
            #pragma unroll
            for (int n = 0; n < 3; ++n) { agi[m][n] = zero4; agh[m][n] = zero4; }

        // ---- phase 1: gi = x_t @ wih^T  (pure register A-operands) ----
        #pragma unroll
        for (int kp = 0; kp < 10; ++kp) {
            int koff = kp*32 + lq*8;
            bfrag bi[3];
            #pragma unroll
            for (int n = 0; n < 3; ++n)
                bi[n] = *(const bfrag*)(wih_s + (n*16 + ul)*328 + koff);
            #pragma unroll
            for (int m = 0; m < 2; ++m)
                #pragma unroll
                for (int n = 0; n < 3; ++n)
                    agi[m][n] = __builtin_amdgcn_mfma_f32_16x16x32_bf16(xcur[m][kp], bi[n], agi[m][n], 0, 0, 0);
        }

        // ---- issue x prefetch for t+1 (completes during stage/phase2) ----
        {
            int tn = (t + 1 < Sd) ? (t + 1) : (Sd - 1);
            const unsigned short* xg = xemb + ((size_t)(side*Sd + tn)*Bd)*EP;
            #pragma unroll
            for (int m = 0; m < 2; ++m) {
                int row = rowbase + m*16 + ul;
                #pragma unroll
                for (int kp = 0; kp < 10; ++kp)
                    xcur[m][kp] = *(const bfrag*)(xg + (size_t)row*EP + kp*32 + lq*8);
            }
        }

        // ---- spin: one coalesced poll over all NCB flags, __all >= t ----
        if (t > 0) {
            while (true) {
                int v = __hip_atomic_load(flg + pollslot, __ATOMIC_RELAXED, __HIP_MEMORY_SCOPE_AGENT);
                if (__all(v >= t)) break;
                __builtin_amdgcn_s_sleep(1);
            }
        }
        asm volatile("" ::: "memory");

        // ---- stage h: 80KB linear, coalesced 8B agent-atomics -> LDS ----
        {
            unsigned long long tv[40];
            #pragma unroll
            for (int j = 0; j < 40; ++j)
                tv[j] = __hip_atomic_load(hg8 + (j*256 + tid),
                                          __ATOMIC_RELAXED, __HIP_MEMORY_SCOPE_AGENT);
            unsigned long long* hs8 = (unsigned long long*)h_s;
            #pragma unroll
            for (int j = 0; j < 40; ++j)
                hs8[j*256 + tid] = tv[j];
        }
        __syncthreads();

        // ---- phase 2: gh = h @ whh^T  (A-frags from LDS) ----
        #pragma unroll
        for (int kp = 0; kp < 10; ++kp) {
            int k0 = kp*32 + lq*8;
            int cb = k0 >> 4, ku = k0 & 15;
            bfrag ah[2], bh[3];
            #pragma unroll
            for (int m = 0; m < 2; ++m) {
                int row = rowbase + m*16 + ul;
                ah[m] = *(const bfrag*)(h_s + cb*2048 + row*16 + ku);
            }
            #pragma unroll
            for (int n = 0; n < 3; ++n)
                bh[n] = *(const bfrag*)(whh_s + (n*16 + ul)*328 + k0);
            #pragma unroll
            for (int m = 0; m < 2; ++m)
                #pragma unroll
                for (int n = 0; n < 3; ++n)
                    agh[m][n] = __builtin_amdgcn_mfma_f32_16x16x32_bf16(ah[m], bh[n], agh[m][n], 0, 0, 0);
        }

        // ---- epilogue: gates, h update -> hn_s ----
        #pragma unroll
        for (int m = 0; m < 2; ++m) {
            #pragma unroll
            for (int i = 0; i < 4; ++i) {
                float gr = agi[m][0][i] + bih_sh[ul]    + agh[m][0][i] + bhh_sh[ul];
                float gz = agi[m][1][i] + bih_sh[16+ul] + agh[m][1][i] + bhh_sh[16+ul];
                float gn = agi[m][2][i] + bih_sh[32+ul];
                float hn_g = agh[m][2][i] + bhh_sh[32+ul];
                float r = sigm(gr);
                float z = sigm(gz);
                float nn = fast_tanh(gn + r*hn_g);
                float hv = (1.f - z)*nn + z*hreg[m][i];
                hreg[m][i] = hv;
                int brow = rowbase + m*16 + lq*4 + i;
                hn_s[brow*16 + ul] = f2bf(hv);
            }
        }
        __syncthreads();

        // ---- coalesced h store: block's contiguous 4KB region ----
        {
            const unsigned long long* src = (const unsigned long long*)hn_s;
            __hip_atomic_store(hn8 + tid,       src[tid],
                               __ATOMIC_RELAXED, __HIP_MEMORY_SCOPE_AGENT);
            __hip_atomic_store(hn8 + 256 + tid, src[256 + tid],
                               __ATOMIC_RELAXED, __HIP_MEMORY_SCOPE_AGENT);
        }
        asm volatile("s_waitcnt vmcnt(0)" ::: "memory");
        __syncthreads();
        if (t < Sd-1 && tid == 0)
            __hip_atomic_store(flg + cid, t+1, __ATOMIC_RELAXED, __HIP_MEMORY_SCOPE_AGENT);

        // ---- attn partials (off critical path) ----
        #pragma unroll
        for (int m = 0; m < 2; ++m) {
            #pragma unroll
            for (int i = 0; i < 4; ++i) {
                int brow = rowbase + m*16 + lq*4 + i;
                float pv = hreg[m][i] * wml_sh[ul];
                pv += __shfl_xor(pv, 1, 64);
                pv += __shfl_xor(pv, 2, 64);
                pv += __shfl_xor(pv, 4, 64);
                pv += __shfl_xor(pv, 8, 64);
                if (ul == 0)
                    part[((size_t)(side*NCB + cid)*Bd + brow)*Sd + t] = pv;
            }
        }
    }
}

// ---------------- reduce attn partials ----------------
__global__ void k_attn(const float* __restrict__ part, const float* __restrict__ bml,
                       const float* __restrict__ bmr, float* __restrict__ attn) {
    int side = blockIdx.x >> 7;
    int b = blockIdx.x & 127;
    int t = threadIdx.x;
    float s = 0.f;
    for (int c = 0; c < NCB; ++c)
        s += part[((size_t)(side*NCB + c)*Bd + b)*Sd + t];
    float bias = side ? bmr[0] : bml[0];
    attn[(size_t)(side*Bd + b)*Sd + t] = sigm(s + bias) + 0.5f;
}

// ---------------- position weights + weighted memory + v_s ----------------
__global__ void k_wmem(const float* __restrict__ embed, const int* __restrict__ text,
                       const float* __restrict__ attn, const int* __restrict__ lens,
                       unsigned short* __restrict__ memw, float* __restrict__ vs) {
    int b = blockIdx.x;
    __shared__ float w_sh[Sd];
    __shared__ int text_s[Sd];
    int memlen = lens[b*4+0], asplen = lens[b*4+1], leftlen = lens[b*4+2];
    int a_start = leftlen - asplen, a_end = leftlen;
    const float* attl = attn + (size_t)b*Sd;
    const float* attr = attn + (size_t)(Bd + b)*Sd;
    if (threadIdx.x < Sd) {
        int i = threadIdx.x;
        int irr = a_end - 1 - i; irr = irr < 0 ? 0 : (irr > Sd-1 ? Sd-1 : irr);
        int ils = i - a_start;   ils = ils < 0 ? 0 : (ils > Sd-1 ? Sd-1 : ils);
        float arr_ = attr[irr], als = attl[ils];
        float w = (i < a_start) ? arr_ : ((i < a_end) ? 0.5f*(arr_+als) : als);
        if (i >= memlen) w = 1.0f;
        w_sh[i] = w;
        text_s[i] = text[b*Sd + i];
    }
    __syncthreads();
    int e = threadIdx.x;
    float acc = 0.f;
    float invm = 1.0f/(float)lens[b*4+0];
    for (int s = 0; s < Sd; ++s) {
        float v = (e < Ed) ? embed[(size_t)text_s[s]*Ed + e] : 0.f;
        float mw = v * w_sh[s];
        memw[((size_t)b*Sd + s)*EP + e] = f2bf(mw);
        acc += mw;
    }
    vs[b*EP + e] = acc * invm;
}

// ---------------- per-batch u = b1 + va@W1a^T + vs@W1s^T ----------------
__global__ void k_u(const float* __restrict__ w1, const float* __restrict__ b1,
                    const float* __restrict__ va, const float* __restrict__ vs,
                    float* __restrict__ u) {
    int b = blockIdx.x;
    __shared__ float va_s[Ed], vs_s[Ed];
    for (int k = threadIdx.x; k < Ed; k += blockDim.x) {
        va_s[k] = va[b*EP+k];
        vs_s[k] = vs[b*EP+k];
    }
    __syncthreads();
    int e = threadIdx.x;
    if (e >= EP) return;
    float acc = 0.f;
    if (e < Ed) {
        acc = b1[e];
        const float* r = w1 + (size_t)e*900;
        for (int k = 0; k < Ed; ++k) acc += va_s[k]*r[300+k];
        for (int k = 0; k < Ed; ++k) acc += vs_s[k]*r[600+k];
    }
    u[b*EP + e] = acc;
}

// ---------------- c[b,s] = w2 . tanh(memw@W1m^T + u)  (MFMA) ----------------
__global__ __launch_bounds__(256) void k_c(const unsigned short* __restrict__ memw,
                   const unsigned short* __restrict__ w1b,
                   const float* __restrict__ u, const float* __restrict__ w2,
                   float* __restrict__ cout) {
    int b = blockIdx.x >> 2;
    int s0 = (blockIdx.x & 3) * 64;
    __shared__ __align__(16) unsigned short A_s[64*328];
    __shared__ __align__(16) unsigned short Bp_s[EP*32];
    __shared__ float u_s[EP], w2_s[EP];
    for (int i = threadIdx.x; i < EP; i += 256) {
        u_s[i] = u[b*EP + i];
        w2_s[i] = (i < Ed) ? w2[i] : 0.f;
    }
    const unsigned short* Ag = memw + ((size_t)b*Sd + s0)*EP;
    for (int c8 = threadIdx.x; c8 < 64*40; c8 += 256) {
        int r = c8 / 40, kk = (c8 - r*40)*8;
        *(bfrag*)(A_s + r*328 + kk) = *(const bfrag*)(Ag + (size_t)r*EP + kk);
    }

    int wave = threadIdx.x >> 6, lane = threadIdx.x & 63;
    int ul = lane & 15, lq = lane >> 4;
    const f32x4 zero4 = {0.f,0.f,0.f,0.f};
    f32x4 acc[20];
    #pragma unroll
    for (int n = 0; n < 20; ++n) acc[n] = zero4;

    for (int kp = 0; kp < 10; ++kp) {
        __syncthreads();
        for (int c8 = threadIdx.x; c8 < EP*4; c8 += 256) {
            int e = c8 >> 2, kk = (c8 & 3)*8;
            *(bfrag*)(Bp_s + e*32 + kk) = *(const bfrag*)(w1b + (size_t)e*EP + kp*32 + kk);
        }
        __syncthreads();
        bfrag a = *(const bfrag*)(A_s + (wave*16 + ul)*328 + kp*32 + lq*8);
        #pragma unroll
        for (int n = 0; n < 20; ++n) {
            bfrag bb = *(const bfrag*)(Bp_s + (n*16 + ul)*32 + lq*8);
            acc[n] = __builtin_amdgcn_mfma_f32_16x16x32_bf16(a, bb, acc[n], 0, 0, 0);
        }
    }
    float cs[4] = {0.f,0.f,0.f,0.f};
    #pragma unroll
    for (int n = 0; n < 20; ++n) {
        int e = n*16 + ul;
        #pragma unroll
        for (int i = 0; i < 4; ++i)
            cs[i] += w2_s[e] * fast_tanh(acc[n][i] + u_s[e]);
    }
    #pragma unroll
    for (int i = 0; i < 4; ++i) {
        float v = cs[i];
        v += __shfl_xor(v, 1, 64); v += __shfl_xor(v, 2, 64);
        v += __shfl_xor(v, 4, 64); v += __shfl_xor(v, 8, 64);
        if (ul == 0) cout[(size_t)b*Sd + s0 + wave*16 + lq*4 + i] = v;
    }
}

// ---------------- softmax over s ----------------
__global__ void k_alpha(const float* __restrict__ cin, float* __restrict__ alpha) {
    int b = blockIdx.x;
    int t = threadIdx.x;
    __shared__ float buf[Sd];
    float v = cin[(size_t)b*Sd + t];
    buf[t] = v; __syncthreads();
    for (int s2 = 128; s2 > 0; s2 >>= 1) {
        if (t < s2) buf[t] = fmaxf(buf[t], buf[t+s2]);
        __syncthreads();
    }
    float mx = buf[0];
    __syncthreads();
    float ex = __expf(v - mx);
    buf[t] = ex; __syncthreads();
    for (int s2 = 128; s2 > 0; s2 >>= 1) {
        if (t < s2) buf[t] += buf[t+s2];
        __syncthreads();
    }
    alpha[(size_t)b*Sd + t] = ex / buf[0];
}

// ---------------- v_ts, v_ns, v_ms, logits, softmax ----------------
__global__ void k_final(const unsigned short* __restrict__ memw, const float* __restrict__ alpha,
                        const float* __restrict__ vs, const float* __restrict__ wm,
                        const float* __restrict__ bm, const float* __restrict__ wd,
                        const float* __restrict__ bd, float* __restrict__ out) {
    int b = blockIdx.x;
    __shared__ float al_s[Sd];
    __shared__ float vns_s[Ed];
    __shared__ float vms_s[Ed];
    __shared__ float lg_s[Pd];
    if (threadIdx.x < Sd) al_s[threadIdx.x] = alpha[(size_t)b*Sd + threadIdx.x];
    __syncthreads();
    int e = threadIdx.x;
    if (e < Ed) {
        float acc = 0.f;
        const unsigned short* mp = memw + (size_t)b*Sd*EP + e;
        for (int s = 0; s < Sd; ++s) acc += bf2f(mp[(size_t)s*EP]) * al_s[s];
        vns_s[e] = acc + vs[b*EP + e];
    }
    __syncthreads();
    if (e < Ed) {
        float acc = bm[e];
        const float* r = wm + (size_t)e*Ed;
        for (int k = 0; k < Ed; ++k) acc += vns_s[k]*r[k];
        vms_s[e] = fast_tanh(acc);
    }
    __syncthreads();
    if (e < Pd) {
        float acc = bd[e];
        const float* r = wd + (size_t)e*Ed;
        for (int k = 0; k < Ed; ++k) acc += vms_s[k]*r[k];
        lg_s[e] = acc;
    }
    __syncthreads();
    if (e < Pd) {
        float m = fmaxf(lg_s[0], fmaxf(lg_s[1], lg_s[2]));
        float den = __expf(lg_s[0]-m)+__expf(lg_s[1]-m)+__expf(lg_s[2]-m);
        out[b*Pd + e] = __expf(lg_s[e]-m)/den;
    }
}

extern "C" void kernel_launch(void* const* d_in, const int* in_sizes, int n_in,
                              void* d_out, int out_size, void* d_ws, size_t ws_size,
                              hipStream_t stream) {
    const float* embed = (const float*)d_in[0];
    const float* w1    = (const float*)d_in[1];
    const float* b1    = (const float*)d_in[2];
    const float* w2    = (const float*)d_in[3];
    const float* wm    = (const float*)d_in[4];
    const float* bm    = (const float*)d_in[5];
    const float* wd    = (const float*)d_in[6];
    const float* bd    = (const float*)d_in[7];
    const float* wih_l = (const float*)d_in[8];
    const float* whh_l = (const float*)d_in[9];
    const float* bih_l = (const float*)d_in[10];
    const float* bhh_l = (const float*)d_in[11];
    const float* wih_r = (const float*)d_in[12];
    const float* whh_r = (const float*)d_in[13];
    const float* bih_r = (const float*)d_in[14];
    const float* bhh_r = (const float*)d_in[15];
    const float* wml   = (const float*)d_in[16];
    const float* bml   = (const float*)d_in[17];
    const float* wmr   = (const float*)d_in[18];
    const float* bmr   = (const float*)d_in[19];
    const int* text    = (const int*)d_in[20];
    const int* aspect  = (const int*)d_in[21];
    const int* xl      = (const int*)d_in[22];
    const int* xr      = (const int*)d_in[23];

    if (ws_size < (size_t)WS_NEEDED) return;
    char* ws = (char*)d_ws;
    int* lens            = (int*)(ws + OFF_LENS);
    int* bars            = (int*)(ws + OFF_BARS);
    float* va            = (float*)(ws + OFF_VA);
    float* vs            = (float*)(ws + OFF_VS);
    float* u             = (float*)(ws + OFF_U);
    float* attn          = (float*)(ws + OFF_ATTN);
    float* alpha         = (float*)(ws + OFF_ALPHA);
    float* c             = (float*)(ws + OFF_C);
    unsigned short* hbuf = (unsigned short*)(ws + OFF_HBUF);
    float* part          = (float*)(ws + OFF_PART);
    unsigned short* w1b  = (unsigned short*)(ws + OFF_W1B);
    unsigned short* xemb = (unsigned short*)(ws + OFF_XEMB);
    unsigned short* memw = (unsigned short*)(ws + OFF_MEMW);

    hipMemsetAsync(ws + OFF_BARS, 0, 4096, stream);
    hipMemsetAsync(ws + OFF_HBUF, 0, 327680, stream);

    k_lengths<<<128, 256, 0, stream>>>(text, aspect, xl, lens);
    k_va     <<<128, 320, 0, stream>>>(embed, aspect, lens, va);
    k_xemb   <<<512, 256, 0, stream>>>(embed, xl, xr, xemb);
    k_w1conv <<<400, 256, 0, stream>>>(w1, w1b);
    k_gru    <<<2*NCB, 256, 0, stream>>>(wih_l, whh_l, bih_l, bhh_l,
                                         wih_r, whh_r, bih_r, bhh_r,
                                         wml, wmr, xemb, hbuf, part, bars);
    k_attn   <<<256, 256, 0, stream>>>(part, bml, bmr, attn);
    k_wmem   <<<128, 320, 0, stream>>>(embed, text, attn, lens, memw, vs);
    k_u      <<<128, 320, 0, stream>>>(w1, b1, va, vs, u);
    k_c      <<<512, 256, 0, stream>>>(memw, w1b, u, w2, c);
    k_alpha  <<<128, 256, 0, stream>>>(c, alpha);
    k_final  <<<128, 320, 0, stream>>>(memw, alpha, vs, wm, bm, wd, bd, (float*)d_out);
}

// Round 6
// 1986.122 us; speedup vs baseline: 1.3096x; 1.0353x over previous
//
#include <hip/hip_runtime.h>
#include <hip/hip_bf16.h>
#include <math.h>

#define Bd 128
#define Sd 256
#define Ad 8
#define Ed 300
#define Hd 300
#define EP 320
#define Pd 3
#define NCB 20   // blocks per GRU side
#define ROWS 48  // 3*16 gate rows per block

typedef __attribute__((ext_vector_type(8))) short bfrag;   // 8 bf16 (4 VGPRs)
typedef __attribute__((ext_vector_type(4))) float f32x4;   // MFMA acc
typedef __attribute__((ext_vector_type(4))) int i32x4;     // 16B chunk

// ---- workspace layout (bytes) ----
#define OFF_LENS   0u           // int[128*4]
#define OFF_BARS   4096u        // int[2*64] : per-side flag group, slot cid
#define OFF_VA     8192u        // float[128*320]
#define OFF_VS     172032u      // float[128*320]
#define OFF_U      335872u      // float[128*320]
#define OFF_ATTN   499712u      // float[2*128*256]
#define OFF_ALPHA  761856u      // float[128*256]
#define OFF_C      892928u      // float[128*256]
#define OFF_HBUF   1024000u     // ushort[2 side][2 parity][20 cb][128 row][16 u]
#define OFF_PART   1351680u     // float[2*20*128*256]
#define OFF_W1B    6594560u     // ushort[320*320]
#define OFF_XEMB   6799360u     // ushort[2*256*128*320]
#define OFF_MEMW   48742400u    // ushort[128*256*320]
#define WS_NEEDED  69713920u

#define HREG 40960              // ushorts per (side,parity) h region

__device__ __forceinline__ unsigned short f2bf(float f) {
    __hip_bfloat16 h = __float2bfloat16(f);
    return *reinterpret_cast<unsigned short*>(&h);
}
__device__ __forceinline__ float bf2f(unsigned short u) {
    __hip_bfloat16 h = *reinterpret_cast<__hip_bfloat16*>(&u);
    return __bfloat162float(h);
}
__device__ __forceinline__ float sigm(float x) {
    return __builtin_amdgcn_rcpf(1.f + __expf(-x));
}
__device__ __forceinline__ float fast_tanh(float x) {
    x = fminf(fmaxf(x, -15.f), 15.f);
    float e = __expf(2.f * x);
    return (e - 1.f) * __builtin_amdgcn_rcpf(e + 1.f);
}

// coherent-at-LLC, fully coalescing 16B load/store (bypass L1+L2 via sc0 sc1)
__device__ __forceinline__ i32x4 llc_load16(const void* p) {
    i32x4 v;
    asm volatile("global_load_dwordx4 %0, %1, off sc0 sc1"
                 : "=v"(v) : "v"(p) : "memory");
    return v;  // NOT ready until s_waitcnt vmcnt
}
__device__ __forceinline__ void llc_store16(void* p, i32x4 v) {
    asm volatile("global_store_dwordx4 %0, %1, off sc0 sc1"
                 :: "v"(p), "v"(v) : "memory");
}

// ---------------- lengths ----------------
__global__ void k_lengths(const int* __restrict__ text, const int* __restrict__ aspect,
                          const int* __restrict__ xl, int* __restrict__ lens) {
    int b = blockIdx.x;
    __shared__ int red[3];
    if (threadIdx.x < 3) red[threadIdx.x] = 0;
    __syncthreads();
    int t = threadIdx.x;
    if (t < Sd) {
        if (text[b*Sd + t] != 0) atomicAdd(&red[0], 1);
        if (xl[b*Sd + t]  != 0) atomicAdd(&red[2], 1);
    }
    if (t < Ad) { if (aspect[b*Ad + t] != 0) atomicAdd(&red[1], 1); }
    __syncthreads();
    if (t < 3) lens[b*4 + t] = red[t];
}

// ---------------- v_a ----------------
__global__ void k_va(const float* __restrict__ embed, const int* __restrict__ aspect,
                     const int* __restrict__ lens, float* __restrict__ va) {
    int b = blockIdx.x;
    __shared__ int aidx[Ad];
    if (threadIdx.x < Ad) aidx[threadIdx.x] = aspect[b*Ad + threadIdx.x];
    __syncthreads();
    float inv = 1.0f / (float)lens[b*4+1];
    for (int e = threadIdx.x; e < EP; e += blockDim.x) {
        float s = 0.f;
        if (e < Ed) {
            for (int a = 0; a < Ad; ++a) s += embed[(size_t)aidx[a]*Ed + e];
        }
        va[b*EP + e] = s * inv;
    }
}

// ---------------- gather embeddings for GRU inputs (bf16, [side][t][b][EP]) ----------------
__global__ void k_xemb(const float* __restrict__ embed, const int* __restrict__ xl,
                       const int* __restrict__ xr, unsigned short* __restrict__ xemb) {
    int side = blockIdx.x >> 8;
    int t = blockIdx.x & 255;
    const int* xs = side ? xr : xl;
    __shared__ int rows_s[Bd];
    if (threadIdx.x < Bd) rows_s[threadIdx.x] = xs[threadIdx.x*Sd + t];
    __syncthreads();
    unsigned short* dst = xemb + ((size_t)(side*Sd + t) * Bd) * EP;
    for (int idx = threadIdx.x; idx < Bd*EP; idx += blockDim.x) {
        int b = idx / EP, k = idx - b*EP;
        float v = (k < Ed) ? embed[(size_t)rows_s[b]*Ed + k] : 0.f;
        dst[idx] = f2bf(v);
    }
}

// ---------------- w1 mem-part -> bf16 padded [320][320] ----------------
__global__ void k_w1conv(const float* __restrict__ w1, unsigned short* __restrict__ w1b) {
    int idx = blockIdx.x*256 + threadIdx.x;
    if (idx >= EP*EP) return;
    int e = idx / EP, k = idx - e*EP;
    float v = (e < Ed && k < Ed) ? w1[(size_t)e*900 + k] : 0.f;
    w1b[idx] = f2bf(v);
}

// ---------------- persistent GRU (both sides) ----------------
// v5: h exchange via PLAIN coalescing dwordx4 with sc0 sc1 (LLC-coherent,
//     L1/L2-bypassing, line-granular) instead of per-lane atomics.
//  - hbuf column-blocked [cb][row][u16]: each block's output contiguous (4KB)
//  - h staged global->LDS linearly; phase2 reads LDS
//  - flags stay atomic (4B); publish after vmcnt(0) drain + syncthreads
__global__ __launch_bounds__(256, 1) void k_gru(
        const float* __restrict__ wih_l, const float* __restrict__ whh_l,
        const float* __restrict__ bih_l, const float* __restrict__ bhh_l,
        const float* __restrict__ wih_r, const float* __restrict__ whh_r,
        const float* __restrict__ bih_r, const float* __restrict__ bhh_r,
        const float* __restrict__ wml, const float* __restrict__ wmr,
        const unsigned short* __restrict__ xemb,
        unsigned short* __restrict__ hbuf,
        float* __restrict__ part, int* __restrict__ bars) {
    // side-parity remap: side0 -> even blockIdx (even XCDs), side1 -> odd
    int side = blockIdx.x & 1;
    int cid  = blockIdx.x >> 1;
    int u0 = cid * 16;
    int tid = threadIdx.x;
    const float* wih = side ? wih_r : wih_l;
    const float* whh = side ? whh_r : whh_l;
    const float* bih = side ? bih_r : bih_l;
    const float* bhh = side ? bhh_r : bhh_l;
    const float* wmv = side ? wmr : wml;

    __shared__ __align__(16) unsigned short wih_s[ROWS*328];
    __shared__ __align__(16) unsigned short whh_s[ROWS*328];
    __shared__ __align__(16) unsigned short h_s[HREG];        // [20 cb][128 row][16 u]
    __shared__ __align__(16) unsigned short hn_s[Bd*16];      // [128 row][16 u]
    __shared__ float bih_sh[ROWS], bhh_sh[ROWS], wml_sh[16];

    for (int idx = tid; idx < ROWS*328; idx += 256) {
        int lr = idx / 328, k = idx - lr*328;
        int g = lr >> 4, ulw = lr & 15, u = u0 + ulw;
        float vi = 0.f, vh = 0.f;
        if (u < Hd && k < Ed) {
            int grow = g*Hd + u;
            vi = wih[(size_t)grow*Ed + k];
            vh = whh[(size_t)grow*Hd + k];
        }
        wih_s[idx] = f2bf(vi);
        whh_s[idx] = f2bf(vh);
    }
    if (tid < ROWS) {
        int g = tid >> 4, ulw = tid & 15, u = u0 + ulw;
        bih_sh[tid] = (u < Hd) ? bih[g*Hd + u] : 0.f;
        bhh_sh[tid] = (u < Hd) ? bhh[g*Hd + u] : 0.f;
    }
    if (tid < 16) {
        int u = u0 + tid;
        wml_sh[tid] = (u < Hd) ? wmv[u] : 0.f;
    }
    __syncthreads();

    int wave = tid >> 6;
    int lane = tid & 63;
    int rowbase = wave * 32;
    int ul = lane & 15;
    int lq = lane >> 4;

    float hreg[2][4] = {{0.f,0.f,0.f,0.f},{0.f,0.f,0.f,0.f}};
    unsigned short* hb = hbuf + (size_t)side * 2 * HREG;   // [parity][HREG]
    int* flg = bars + side*64;                             // flg[cid] = ready gen
    const f32x4 zero4 = {0.f, 0.f, 0.f, 0.f};
    int pollslot = (lane < NCB) ? lane : (NCB-1);

    // preload x fragments for t=0
    bfrag xcur[2][10];
    {
        const unsigned short* xg = xemb + ((size_t)(side*Sd + 0)*Bd)*EP;
        #pragma unroll
        for (int m = 0; m < 2; ++m) {
            int row = rowbase + m*16 + ul;
            #pragma unroll
            for (int kp = 0; kp < 10; ++kp)
                xcur[m][kp] = *(const bfrag*)(xg + (size_t)row*EP + kp*32 + lq*8);
        }
    }

    #pragma unroll 1
    for (int t = 0; t < Sd; ++t) {
        const unsigned short* hg = hb + (size_t)(t & 1)*HREG;
        unsigned short* hn = hb + (size_t)((t+1) & 1)*HREG + (size_t)cid*2048;

        f32x4 agi[2][3], agh[2][3];
        #pragma unroll
        for (int m = 0; m < 2; ++m)
            #pragma unroll
            for (int n = 0; n < 3; ++n) { agi[m][n] = zero4; agh[m][n] = zero4; }

        // ---- phase 1: gi = x_t @ wih^T  (pure register A-operands) ----
        #pragma unroll
        for (int kp = 0; kp < 10; ++kp) {
            int koff = kp*32 + lq*8;
            bfrag bi[3];
            #pragma unroll
            for (int n = 0; n < 3; ++n)
                bi[n] = *(const bfrag*)(wih_s + (n*16 + ul)*328 + koff);
            #pragma unroll
            for (int m = 0; m < 2; ++m)
                #pragma unroll
                for (int n = 0; n < 3; ++n)
                    agi[m][n] = __builtin_amdgcn_mfma_f32_16x16x32_bf16(xcur[m][kp], bi[n], agi[m][n], 0, 0, 0);
        }

        // ---- issue x prefetch for t+1 (completes during stage/phase2) ----
        {
            int tn = (t + 1 < Sd) ? (t + 1) : (Sd - 1);
            const unsigned short* xg = xemb + ((size_t)(side*Sd + tn)*Bd)*EP;
            #pragma unroll
            for (int m = 0; m < 2; ++m) {
                int row = rowbase + m*16 + ul;
                #pragma unroll
                for (int kp = 0; kp < 10; ++kp)
                    xcur[m][kp] = *(const bfrag*)(xg + (size_t)row*EP + kp*32 + lq*8);
            }
        }

        // ---- spin: one coalesced poll over all NCB flags, __all >= t ----
        if (t > 0) {
            while (true) {
                int v = __hip_atomic_load(flg + pollslot, __ATOMIC_RELAXED, __HIP_MEMORY_SCOPE_AGENT);
                if (__all(v >= t)) break;
                __builtin_amdgcn_s_sleep(1);
            }
        }
        asm volatile("" ::: "memory");

        // ---- stage h: 80KB linear, coalesced dwordx4 sc0 sc1 -> LDS ----
        {
            i32x4 tv[20];
            #pragma unroll
            for (int j = 0; j < 20; ++j)
                tv[j] = llc_load16(hg + (size_t)(j*256 + tid)*8);
            asm volatile("s_waitcnt vmcnt(0)" ::: "memory");
            __builtin_amdgcn_sched_barrier(0);
            i32x4* hs16 = (i32x4*)h_s;
            #pragma unroll
            for (int j = 0; j < 20; ++j)
                hs16[j*256 + tid] = tv[j];
        }
        __syncthreads();

        // ---- phase 2: gh = h @ whh^T  (A-frags from LDS) ----
        #pragma unroll
        for (int kp = 0; kp < 10; ++kp) {
            int k0 = kp*32 + lq*8;
            int cb = k0 >> 4, ku = k0 & 15;
            bfrag ah[2], bh[3];
            #pragma unroll
            for (int m = 0; m < 2; ++m) {
                int row = rowbase + m*16 + ul;
                ah[m] = *(const bfrag*)(h_s + cb*2048 + row*16 + ku);
            }
            #pragma unroll
            for (int n = 0; n < 3; ++n)
                bh[n] = *(const bfrag*)(whh_s + (n*16 + ul)*328 + k0);
            #pragma unroll
            for (int m = 0; m < 2; ++m)
                #pragma unroll
                for (int n = 0; n < 3; ++n)
                    agh[m][n] = __builtin_amdgcn_mfma_f32_16x16x32_bf16(ah[m], bh[n], agh[m][n], 0, 0, 0);
        }

        // ---- epilogue: gates, h update -> hn_s ----
        #pragma unroll
        for (int m = 0; m < 2; ++m) {
            #pragma unroll
            for (int i = 0; i < 4; ++i) {
                float gr = agi[m][0][i] + bih_sh[ul]    + agh[m][0][i] + bhh_sh[ul];
                float gz = agi[m][1][i] + bih_sh[16+ul] + agh[m][1][i] + bhh_sh[16+ul];
                float gn = agi[m][2][i] + bih_sh[32+ul];
                float hn_g = agh[m][2][i] + bhh_sh[32+ul];
                float r = sigm(gr);
                float z = sigm(gz);
                float nn = fast_tanh(gn + r*hn_g);
                float hv = (1.f - z)*nn + z*hreg[m][i];
                hreg[m][i] = hv;
                int brow = rowbase + m*16 + lq*4 + i;
                hn_s[brow*16 + ul] = f2bf(hv);
            }
        }
        __syncthreads();

        // ---- coalesced h store: block's contiguous 4KB region ----
        {
            const i32x4* src = (const i32x4*)hn_s;
            llc_store16(hn + (size_t)tid*8, src[tid]);
        }
        asm volatile("s_waitcnt vmcnt(0)" ::: "memory");
        __syncthreads();
        if (t < Sd-1 && tid == 0)
            __hip_atomic_store(flg + cid, t+1, __ATOMIC_RELAXED, __HIP_MEMORY_SCOPE_AGENT);

        // ---- attn partials (off critical path) ----
        #pragma unroll
        for (int m = 0; m < 2; ++m) {
            #pragma unroll
            for (int i = 0; i < 4; ++i) {
                int brow = rowbase + m*16 + lq*4 + i;
                float pv = hreg[m][i] * wml_sh[ul];
                pv += __shfl_xor(pv, 1, 64);
                pv += __shfl_xor(pv, 2, 64);
                pv += __shfl_xor(pv, 4, 64);
                pv += __shfl_xor(pv, 8, 64);
                if (ul == 0)
                    part[((size_t)(side*NCB + cid)*Bd + brow)*Sd + t] = pv;
            }
        }
    }
}

// ---------------- reduce attn partials ----------------
__global__ void k_attn(const float* __restrict__ part, const float* __restrict__ bml,
                       const float* __restrict__ bmr, float* __restrict__ attn) {
    int side = blockIdx.x >> 7;
    int b = blockIdx.x & 127;
    int t = threadIdx.x;
    float s = 0.f;
    for (int c = 0; c < NCB; ++c)
        s += part[((size_t)(side*NCB + c)*Bd + b)*Sd + t];
    float bias = side ? bmr[0] : bml[0];
    attn[(size_t)(side*Bd + b)*Sd + t] = sigm(s + bias) + 0.5f;
}

// ---------------- position weights + weighted memory + v_s ----------------
__global__ void k_wmem(const float* __restrict__ embed, const int* __restrict__ text,
                       const float* __restrict__ attn, const int* __restrict__ lens,
                       unsigned short* __restrict__ memw, float* __restrict__ vs) {
    int b = blockIdx.x;
    __shared__ float w_sh[Sd];
    __shared__ int text_s[Sd];
    int memlen = lens[b*4+0], asplen = lens[b*4+1], leftlen = lens[b*4+2];
    int a_start = leftlen - asplen, a_end = leftlen;
    const float* attl = attn + (size_t)b*Sd;
    const float* attr = attn + (size_t)(Bd + b)*Sd;
    if (threadIdx.x < Sd) {
        int i = threadIdx.x;
        int irr = a_end - 1 - i; irr = irr < 0 ? 0 : (irr > Sd-1 ? Sd-1 : irr);
        int ils = i - a_start;   ils = ils < 0 ? 0 : (ils > Sd-1 ? Sd-1 : ils);
        float arr_ = attr[irr], als = attl[ils];
        float w = (i < a_start) ? arr_ : ((i < a_end) ? 0.5f*(arr_+als) : als);
        if (i >= memlen) w = 1.0f;
        w_sh[i] = w;
        text_s[i] = text[b*Sd + i];
    }
    __syncthreads();
    int e = threadIdx.x;
    float acc = 0.f;
    float invm = 1.0f/(float)lens[b*4+0];
    for (int s = 0; s < Sd; ++s) {
        float v = (e < Ed) ? embed[(size_t)text_s[s]*Ed + e] : 0.f;
        float mw = v * w_sh[s];
        memw[((size_t)b*Sd + s)*EP + e] = f2bf(mw);
        acc += mw;
    }
    vs[b*EP + e] = acc * invm;
}

// ---------------- per-batch u = b1 + va@W1a^T + vs@W1s^T ----------------
__global__ void k_u(const float* __restrict__ w1, const float* __restrict__ b1,
                    const float* __restrict__ va, const float* __restrict__ vs,
                    float* __restrict__ u) {
    int b = blockIdx.x;
    __shared__ float va_s[Ed], vs_s[Ed];
    for (int k = threadIdx.x; k < Ed; k += blockDim.x) {
        va_s[k] = va[b*EP+k];
        vs_s[k] = vs[b*EP+k];
    }
    __syncthreads();
    int e = threadIdx.x;
    if (e >= EP) return;
    float acc = 0.f;
    if (e < Ed) {
        acc = b1[e];
        const float* r = w1 + (size_t)e*900;
        for (int k = 0; k < Ed; ++k) acc += va_s[k]*r[300+k];
        for (int k = 0; k < Ed; ++k) acc += vs_s[k]*r[600+k];
    }
    u[b*EP + e] = acc;
}

// ---------------- c[b,s] = w2 . tanh(memw@W1m^T + u)  (MFMA) ----------------
__global__ __launch_bounds__(256) void k_c(const unsigned short* __restrict__ memw,
                   const unsigned short* __restrict__ w1b,
                   const float* __restrict__ u, const float* __restrict__ w2,
                   float* __restrict__ cout) {
    int b = blockIdx.x >> 2;
    int s0 = (blockIdx.x & 3) * 64;
    __shared__ __align__(16) unsigned short A_s[64*328];
    __shared__ __align__(16) unsigned short Bp_s[EP*32];
    __shared__ float u_s[EP], w2_s[EP];
    for (int i = threadIdx.x; i < EP; i += 256) {
        u_s[i] = u[b*EP + i];
        w2_s[i] = (i < Ed) ? w2[i] : 0.f;
    }
    const unsigned short* Ag = memw + ((size_t)b*Sd + s0)*EP;
    for (int c8 = threadIdx.x; c8 < 64*40; c8 += 256) {
        int r = c8 / 40, kk = (c8 - r*40)*8;
        *(bfrag*)(A_s + r*328 + kk) = *(const bfrag*)(Ag + (size_t)r*EP + kk);
    }

    int wave = threadIdx.x >> 6, lane = threadIdx.x & 63;
    int ul = lane & 15, lq = lane >> 4;
    const f32x4 zero4 = {0.f,0.f,0.f,0.f};
    f32x4 acc[20];
    #pragma unroll
    for (int n = 0; n < 20; ++n) acc[n] = zero4;

    for (int kp = 0; kp < 10; ++kp) {
        __syncthreads();
        for (int c8 = threadIdx.x; c8 < EP*4; c8 += 256) {
            int e = c8 >> 2, kk = (c8 & 3)*8;
            *(bfrag*)(Bp_s + e*32 + kk) = *(const bfrag*)(w1b + (size_t)e*EP + kp*32 + kk);
        }
        __syncthreads();
        bfrag a = *(const bfrag*)(A_s + (wave*16 + ul)*328 + kp*32 + lq*8);
        #pragma unroll
        for (int n = 0; n < 20; ++n) {
            bfrag bb = *(const bfrag*)(Bp_s + (n*16 + ul)*32 + lq*8);
            acc[n] = __builtin_amdgcn_mfma_f32_16x16x32_bf16(a, bb, acc[n], 0, 0, 0);
        }
    }
    float cs[4] = {0.f,0.f,0.f,0.f};
    #pragma unroll
    for (int n = 0; n < 20; ++n) {
        int e = n*16 + ul;
        #pragma unroll
        for (int i = 0; i < 4; ++i)
            cs[i] += w2_s[e] * fast_tanh(acc[n][i] + u_s[e]);
    }
    #pragma unroll
    for (int i = 0; i < 4; ++i) {
        float v = cs[i];
        v += __shfl_xor(v, 1, 64); v += __shfl_xor(v, 2, 64);
        v += __shfl_xor(v, 4, 64); v += __shfl_xor(v, 8, 64);
        if (ul == 0) cout[(size_t)b*Sd + s0 + wave*16 + lq*4 + i] = v;
    }
}

// ---------------- softmax over s ----------------
__global__ void k_alpha(const float* __restrict__ cin, float* __restrict__ alpha) {
    int b = blockIdx.x;
    int t = threadIdx.x;
    __shared__ float buf[Sd];
    float v = cin[(size_t)b*Sd + t];
    buf[t] = v; __syncthreads();
    for (int s2 = 128; s2 > 0; s2 >>= 1) {
        if (t < s2) buf[t] = fmaxf(buf[t], buf[t+s2]);
        __syncthreads();
    }
    float mx = buf[0];
    __syncthreads();
    float ex = __expf(v - mx);
    buf[t] = ex; __syncthreads();
    for (int s2 = 128; s2 > 0; s2 >>= 1) {
        if (t < s2) buf[t] += buf[t+s2];
        __syncthreads();
    }
    alpha[(size_t)b*Sd + t] = ex / buf[0];
}

// ---------------- v_ts, v_ns, v_ms, logits, softmax ----------------
__global__ void k_final(const unsigned short* __restrict__ memw, const float* __restrict__ alpha,
                        const float* __restrict__ vs, const float* __restrict__ wm,
                        const float* __restrict__ bm, const float* __restrict__ wd,
                        const float* __restrict__ bd, float* __restrict__ out) {
    int b = blockIdx.x;
    __shared__ float al_s[Sd];
    __shared__ float vns_s[Ed];
    __shared__ float vms_s[Ed];
    __shared__ float lg_s[Pd];
    if (threadIdx.x < Sd) al_s[threadIdx.x] = alpha[(size_t)b*Sd + threadIdx.x];
    __syncthreads();
    int e = threadIdx.x;
    if (e < Ed) {
        float acc = 0.f;
        const unsigned short* mp = memw + (size_t)b*Sd*EP + e;
        for (int s = 0; s < Sd; ++s) acc += bf2f(mp[(size_t)s*EP]) * al_s[s];
        vns_s[e] = acc + vs[b*EP + e];
    }
    __syncthreads();
    if (e < Ed) {
        float acc = bm[e];
        const float* r = wm + (size_t)e*Ed;
        for (int k = 0; k < Ed; ++k) acc += vns_s[k]*r[k];
        vms_s[e] = fast_tanh(acc);
    }
    __syncthreads();
    if (e < Pd) {
        float acc = bd[e];
        const float* r = wd + (size_t)e*Ed;
        for (int k = 0; k < Ed; ++k) acc += vms_s[k]*r[k];
        lg_s[e] = acc;
    }
    __syncthreads();
    if (e < Pd) {
        float m = fmaxf(lg_s[0], fmaxf(lg_s[1], lg_s[2]));
        float den = __expf(lg_s[0]-m)+__expf(lg_s[1]-m)+__expf(lg_s[2]-m);
        out[b*Pd + e] = __expf(lg_s[e]-m)/den;
    }
}

extern "C" void kernel_launch(void* const* d_in, const int* in_sizes, int n_in,
                              void* d_out, int out_size, void* d_ws, size_t ws_size,
                              hipStream_t stream) {
    const float* embed = (const float*)d_in[0];
    const float* w1    = (const float*)d_in[1];
    const float* b1    = (const float*)d_in[2];
    const float* w2    = (const float*)d_in[3];
    const float* wm    = (const float*)d_in[4];
    const float* bm    = (const float*)d_in[5];
    const float* wd    = (const float*)d_in[6];
    const float* bd    = (const float*)d_in[7];
    const float* wih_l = (const float*)d_in[8];
    const float* whh_l = (const float*)d_in[9];
    const float* bih_l = (const float*)d_in[10];
    const float* bhh_l = (const float*)d_in[11];
    const float* wih_r = (const float*)d_in[12];
    const float* whh_r = (const float*)d_in[13];
    const float* bih_r = (const float*)d_in[14];
    const float* bhh_r = (const float*)d_in[15];
    const float* wml   = (const float*)d_in[16];
    const float* bml   = (const float*)d_in[17];
    const float* wmr   = (const float*)d_in[18];
    const float* bmr   = (const float*)d_in[19];
    const int* text    = (const int*)d_in[20];
    const int* aspect  = (const int*)d_in[21];
    const int* xl      = (const int*)d_in[22];
    const int* xr      = (const int*)d_in[23];

    if (ws_size < (size_t)WS_NEEDED) return;
    char* ws = (char*)d_ws;
    int* lens            = (int*)(ws + OFF_LENS);
    int* bars            = (int*)(ws + OFF_BARS);
    float* va            = (float*)(ws + OFF_VA);
    float* vs            = (float*)(ws + OFF_VS);
    float* u             = (float*)(ws + OFF_U);
    float* attn          = (float*)(ws + OFF_ATTN);
    float* alpha         = (float*)(ws + OFF_ALPHA);
    float* c             = (float*)(ws + OFF_C);
    unsigned short* hbuf = (unsigned short*)(ws + OFF_HBUF);
    float* part          = (float*)(ws + OFF_PART);
    unsigned short* w1b  = (unsigned short*)(ws + OFF_W1B);
    unsigned short* xemb = (unsigned short*)(ws + OFF_XEMB);
    unsigned short* memw = (unsigned short*)(ws + OFF_MEMW);

    hipMemsetAsync(ws + OFF_BARS, 0, 4096, stream);
    hipMemsetAsync(ws + OFF_HBUF, 0, 327680, stream);

    k_lengths<<<128, 256, 0, stream>>>(text, aspect, xl, lens);
    k_va     <<<128, 320, 0, stream>>>(embed, aspect, lens, va);
    k_xemb   <<<512, 256, 0, stream>>>(embed, xl, xr, xemb);
    k_w1conv <<<400, 256, 0, stream>>>(w1, w1b);
    k_gru    <<<2*NCB, 256, 0, stream>>>(wih_l, whh_l, bih_l, bhh_l,
                                         wih_r, whh_r, bih_r, bhh_r,
                                         wml, wmr, xemb, hbuf, part, bars);
    k_attn   <<<256, 256, 0, stream>>>(part, bml, bmr, attn);
    k_wmem   <<<128, 320, 0, stream>>>(embed, text, attn, lens, memw, vs);
    k_u      <<<128, 320, 0, stream>>>(w1, b1, va, vs, u);
    k_c      <<<512, 256, 0, stream>>>(memw, w1b, u, w2, c);
    k_alpha  <<<128, 256, 0, stream>>>(c, alpha);
    k_final  <<<128, 320, 0, stream>>>(memw, alpha, vs, wm, bm, wd, bd, (float*)d_out);
}

// Round 7
// 1913.982 us; speedup vs baseline: 1.3589x; 1.0377x over previous
//
#include <hip/hip_runtime.h>
#include <hip/hip_bf16.h>
#include <math.h>

#define Bd 128
#define Sd 256
#define Ad 8
#define Ed 300
#define Hd 300
#define EP 320
#define Pd 3
#define NCB 20   // blocks per GRU side
#define ROWS 48  // 3*16 gate rows per block
#define GRID_GRU 160  // sparse launch: workers are bid%8 in {0,1}

typedef __attribute__((ext_vector_type(8))) short bfrag;   // 8 bf16 (4 VGPRs)
typedef __attribute__((ext_vector_type(4))) float f32x4;   // MFMA acc
typedef __attribute__((ext_vector_type(4))) int i32x4;     // 16B chunk

// ---- workspace layout (bytes) ----
#define OFF_LENS   0u           // int[128*4]
#define OFF_BARS   4096u        // int[2*64] : per-side flag group, slot cid
#define OFF_VA     8192u        // float[128*320]
#define OFF_VS     172032u      // float[128*320]
#define OFF_U      335872u      // float[128*320]
#define OFF_ATTN   499712u      // float[2*128*256]
#define OFF_ALPHA  761856u      // float[128*256]
#define OFF_C      892928u      // float[128*256]
#define OFF_HBUF   1024000u     // ushort[2 side][2 parity][20 cb][128 row][16 u]
#define OFF_PART   1351680u     // float[2*20*128*256]
#define OFF_W1B    6594560u     // ushort[320*320]
#define OFF_XEMB   6799360u     // ushort[2*256*128*320]
#define OFF_MEMW   48742400u    // ushort[128*256*320]
#define WS_NEEDED  69713920u

#define HREG 40960              // ushorts per (side,parity) h region

__device__ __forceinline__ unsigned short f2bf(float f) {
    __hip_bfloat16 h = __float2bfloat16(f);
    return *reinterpret_cast<unsigned short*>(&h);
}
__device__ __forceinline__ float bf2f(unsigned short u) {
    __hip_bfloat16 h = *reinterpret_cast<__hip_bfloat16*>(&u);
    return __bfloat162float(h);
}
__device__ __forceinline__ float sigm(float x) {
    return __builtin_amdgcn_rcpf(1.f + __expf(-x));
}
__device__ __forceinline__ float fast_tanh(float x) {
    x = fminf(fmaxf(x, -15.f), 15.f);
    float e = __expf(2.f * x);
    return (e - 1.f) * __builtin_amdgcn_rcpf(e + 1.f);
}

// coherent-at-LLC, fully coalescing 16B load/store (bypass L1+L2 via sc0 sc1)
__device__ __forceinline__ i32x4 llc_load16(const void* p) {
    i32x4 v;
    asm volatile("global_load_dwordx4 %0, %1, off sc0 sc1"
                 : "=v"(v) : "v"(p) : "memory");
    return v;  // NOT ready until s_waitcnt vmcnt
}
__device__ __forceinline__ void llc_store16(void* p, i32x4 v) {
    asm volatile("global_store_dwordx4 %0, %1, off sc0 sc1"
                 :: "v"(p), "v"(v) : "memory");
}

// ---------------- lengths ----------------
__global__ void k_lengths(const int* __restrict__ text, const int* __restrict__ aspect,
                          const int* __restrict__ xl, int* __restrict__ lens) {
    int b = blockIdx.x;
    __shared__ int red[3];
    if (threadIdx.x < 3) red[threadIdx.x] = 0;
    __syncthreads();
    int t = threadIdx.x;
    if (t < Sd) {
        if (text[b*Sd + t] != 0) atomicAdd(&red[0], 1);
        if (xl[b*Sd + t]  != 0) atomicAdd(&red[2], 1);
    }
    if (t < Ad) { if (aspect[b*Ad + t] != 0) atomicAdd(&red[1], 1); }
    __syncthreads();
    if (t < 3) lens[b*4 + t] = red[t];
}

// ---------------- v_a ----------------
__global__ void k_va(const float* __restrict__ embed, const int* __restrict__ aspect,
                     const int* __restrict__ lens, float* __restrict__ va) {
    int b = blockIdx.x;
    __shared__ int aidx[Ad];
    if (threadIdx.x < Ad) aidx[threadIdx.x] = aspect[b*Ad + threadIdx.x];
    __syncthreads();
    float inv = 1.0f / (float)lens[b*4+1];
    for (int e = threadIdx.x; e < EP; e += blockDim.x) {
        float s = 0.f;
        if (e < Ed) {
            for (int a = 0; a < Ad; ++a) s += embed[(size_t)aidx[a]*Ed + e];
        }
        va[b*EP + e] = s * inv;
    }
}

// ---------------- gather embeddings for GRU inputs (bf16, [side][t][b][EP]) ----------------
__global__ void k_xemb(const float* __restrict__ embed, const int* __restrict__ xl,
                       const int* __restrict__ xr, unsigned short* __restrict__ xemb) {
    int side = blockIdx.x >> 8;
    int t = blockIdx.x & 255;
    const int* xs = side ? xr : xl;
    __shared__ int rows_s[Bd];
    if (threadIdx.x < Bd) rows_s[threadIdx.x] = xs[threadIdx.x*Sd + t];
    __syncthreads();
    unsigned short* dst = xemb + ((size_t)(side*Sd + t) * Bd) * EP;
    for (int idx = threadIdx.x; idx < Bd*EP; idx += blockDim.x) {
        int b = idx / EP, k = idx - b*EP;
        float v = (k < Ed) ? embed[(size_t)rows_s[b]*Ed + k] : 0.f;
        dst[idx] = f2bf(v);
    }
}

// ---------------- w1 mem-part -> bf16 padded [320][320] ----------------
__global__ void k_w1conv(const float* __restrict__ w1, unsigned short* __restrict__ w1b) {
    int idx = blockIdx.x*256 + threadIdx.x;
    if (idx >= EP*EP) return;
    int e = idx / EP, k = idx - e*EP;
    float v = (e < Ed && k < Ed) ? w1[(size_t)e*900 + k] : 0.f;
    w1b[idx] = f2bf(v);
}

// ---------------- persistent GRU (both sides) ----------------
// v6: XCD-pinned sparse launch. Grid=160; workers are bid%8 in {0,1}
//   (side = bid%8, cid = bid/8). Under the empirical round-robin XCD map
//   each side's 20 blocks share ONE XCD's L2 -> x tile fetched from HBM once
//   per step instead of ~4x. Pure perf: h exchange stays agent-scope LLC ops,
//   so correctness does not depend on placement.
__global__ __launch_bounds__(256, 1) void k_gru(
        const float* __restrict__ wih_l, const float* __restrict__ whh_l,
        const float* __restrict__ bih_l, const float* __restrict__ bhh_l,
        const float* __restrict__ wih_r, const float* __restrict__ whh_r,
        const float* __restrict__ bih_r, const float* __restrict__ bhh_r,
        const float* __restrict__ wml, const float* __restrict__ wmr,
        const unsigned short* __restrict__ xemb,
        unsigned short* __restrict__ hbuf,
        float* __restrict__ part, int* __restrict__ bars) {
    int lane8 = blockIdx.x & 7;
    if (lane8 > 1) return;            // non-worker XCD lanes exit
    int side = lane8;
    int cid  = blockIdx.x >> 3;       // 0..19
    int u0 = cid * 16;
    int tid = threadIdx.x;
    const float* wih = side ? wih_r : wih_l;
    const float* whh = side ? whh_r : whh_l;
    const float* bih = side ? bih_r : bih_l;
    const float* bhh = side ? bhh_r : bhh_l;
    const float* wmv = side ? wmr : wml;

    __shared__ __align__(16) unsigned short wih_s[ROWS*328];
    __shared__ __align__(16) unsigned short whh_s[ROWS*328];
    __shared__ __align__(16) unsigned short h_s[HREG];        // [20 cb][128 row][16 u]
    __shared__ __align__(16) unsigned short hn_s[Bd*16];      // [128 row][16 u]
    __shared__ float bih_sh[ROWS], bhh_sh[ROWS], wml_sh[16];

    for (int idx = tid; idx < ROWS*328; idx += 256) {
        int lr = idx / 328, k = idx - lr*328;
        int g = lr >> 4, ulw = lr & 15, u = u0 + ulw;
        float vi = 0.f, vh = 0.f;
        if (u < Hd && k < Ed) {
            int grow = g*Hd + u;
            vi = wih[(size_t)grow*Ed + k];
            vh = whh[(size_t)grow*Hd + k];
        }
        wih_s[idx] = f2bf(vi);
        whh_s[idx] = f2bf(vh);
    }
    if (tid < ROWS) {
        int g = tid >> 4, ulw = tid & 15, u = u0 + ulw;
        bih_sh[tid] = (u < Hd) ? bih[g*Hd + u] : 0.f;
        bhh_sh[tid] = (u < Hd) ? bhh[g*Hd + u] : 0.f;
    }
    if (tid < 16) {
        int u = u0 + tid;
        wml_sh[tid] = (u < Hd) ? wmv[u] : 0.f;
    }
    __syncthreads();

    int wave = tid >> 6;
    int lane = tid & 63;
    int rowbase = wave * 32;
    int ul = lane & 15;
    int lq = lane >> 4;

    float hreg[2][4] = {{0.f,0.f,0.f,0.f},{0.f,0.f,0.f,0.f}};
    unsigned short* hb = hbuf + (size_t)side * 2 * HREG;   // [parity][HREG]
    int* flg = bars + side*64;                             // flg[cid] = ready gen
    const f32x4 zero4 = {0.f, 0.f, 0.f, 0.f};
    int pollslot = (lane < NCB) ? lane : (NCB-1);

    // preload x fragments for t=0
    bfrag xcur[2][10];
    {
        const unsigned short* xg = xemb + ((size_t)(side*Sd + 0)*Bd)*EP;
        #pragma unroll
        for (int m = 0; m < 2; ++m) {
            int row = rowbase + m*16 + ul;
            #pragma unroll
            for (int kp = 0; kp < 10; ++kp)
                xcur[m][kp] = *(const bfrag*)(xg + (size_t)row*EP + kp*32 + lq*8);
        }
    }

    #pragma unroll 1
    for (int t = 0; t < Sd; ++t) {
        const unsigned short* hg = hb + (size_t)(t & 1)*HREG;
        unsigned short* hn = hb + (size_t)((t+1) & 1)*HREG + (size_t)cid*2048;

        f32x4 agi[2][3], agh[2][3];
        #pragma unroll
        for (int m = 0; m < 2; ++m)
            #pragma unroll
            for (int n = 0; n < 3; ++n) { agi[m][n] = zero4; agh[m][n] = zero4; }

        // ---- phase 1: gi = x_t @ wih^T  (pure register A-operands) ----
        #pragma unroll
        for (int kp = 0; kp < 10; ++kp) {
            int koff = kp*32 + lq*8;
            bfrag bi[3];
            #pragma unroll
            for (int n = 0; n < 3; ++n)
                bi[n] = *(const bfrag*)(wih_s + (n*16 + ul)*328 + koff);
            #pragma unroll
            for (int m = 0; m < 2; ++m)
                #pragma unroll
                for (int n = 0; n < 3; ++n)
                    agi[m][n] = __builtin_amdgcn_mfma_f32_16x16x32_bf16(xcur[m][kp], bi[n], agi[m][n], 0, 0, 0);
        }

        // ---- issue x prefetch for t+1 (completes during stage/phase2) ----
        {
            int tn = (t + 1 < Sd) ? (t + 1) : (Sd - 1);
            const unsigned short* xg = xemb + ((size_t)(side*Sd + tn)*Bd)*EP;
            #pragma unroll
            for (int m = 0; m < 2; ++m) {
                int row = rowbase + m*16 + ul;
                #pragma unroll
                for (int kp = 0; kp < 10; ++kp)
                    xcur[m][kp] = *(const bfrag*)(xg + (size_t)row*EP + kp*32 + lq*8);
            }
        }

        // ---- spin: one coalesced poll over all NCB flags, __all >= t ----
        if (t > 0) {
            while (true) {
                int v = __hip_atomic_load(flg + pollslot, __ATOMIC_RELAXED, __HIP_MEMORY_SCOPE_AGENT);
                if (__all(v >= t)) break;
                __builtin_amdgcn_s_sleep(1);
            }
        }
        asm volatile("" ::: "memory");

        // ---- stage h: 80KB linear, coalesced dwordx4 sc0 sc1 -> LDS ----
        {
            i32x4 tv[20];
            #pragma unroll
            for (int j = 0; j < 20; ++j)
                tv[j] = llc_load16(hg + (size_t)(j*256 + tid)*8);
            asm volatile("s_waitcnt vmcnt(0)" ::: "memory");
            __builtin_amdgcn_sched_barrier(0);
            i32x4* hs16 = (i32x4*)h_s;
            #pragma unroll
            for (int j = 0; j < 20; ++j)
                hs16[j*256 + tid] = tv[j];
        }
        __syncthreads();

        // ---- phase 2: gh = h @ whh^T  (A-frags from LDS) ----
        #pragma unroll
        for (int kp = 0; kp < 10; ++kp) {
            int k0 = kp*32 + lq*8;
            int cb = k0 >> 4, ku = k0 & 15;
            bfrag ah[2], bh[3];
            #pragma unroll
            for (int m = 0; m < 2; ++m) {
                int row = rowbase + m*16 + ul;
                ah[m] = *(const bfrag*)(h_s + cb*2048 + row*16 + ku);
            }
            #pragma unroll
            for (int n = 0; n < 3; ++n)
                bh[n] = *(const bfrag*)(whh_s + (n*16 + ul)*328 + k0);
            #pragma unroll
            for (int m = 0; m < 2; ++m)
                #pragma unroll
                for (int n = 0; n < 3; ++n)
                    agh[m][n] = __builtin_amdgcn_mfma_f32_16x16x32_bf16(ah[m], bh[n], agh[m][n], 0, 0, 0);
        }

        // ---- epilogue: gates, h update -> hn_s ----
        #pragma unroll
        for (int m = 0; m < 2; ++m) {
            #pragma unroll
            for (int i = 0; i < 4; ++i) {
                float gr = agi[m][0][i] + bih_sh[ul]    + agh[m][0][i] + bhh_sh[ul];
                float gz = agi[m][1][i] + bih_sh[16+ul] + agh[m][1][i] + bhh_sh[16+ul];
                float gn = agi[m][2][i] + bih_sh[32+ul];
                float hn_g = agh[m][2][i] + bhh_sh[32+ul];
                float r = sigm(gr);
                float z = sigm(gz);
                float nn = fast_tanh(gn + r*hn_g);
                float hv = (1.f - z)*nn + z*hreg[m][i];
                hreg[m][i] = hv;
                int brow = rowbase + m*16 + lq*4 + i;
                hn_s[brow*16 + ul] = f2bf(hv);
            }
        }
        __syncthreads();

        // ---- coalesced h store: block's contiguous 4KB region ----
        {
            const i32x4* src = (const i32x4*)hn_s;
            llc_store16(hn + (size_t)tid*8, src[tid]);
        }
        asm volatile("s_waitcnt vmcnt(0)" ::: "memory");
        __syncthreads();
        if (t < Sd-1 && tid == 0)
            __hip_atomic_store(flg + cid, t+1, __ATOMIC_RELAXED, __HIP_MEMORY_SCOPE_AGENT);

        // ---- attn partials (off critical path) ----
        #pragma unroll
        for (int m = 0; m < 2; ++m) {
            #pragma unroll
            for (int i = 0; i < 4; ++i) {
                int brow = rowbase + m*16 + lq*4 + i;
                float pv = hreg[m][i] * wml_sh[ul];
                pv += __shfl_xor(pv, 1, 64);
                pv += __shfl_xor(pv, 2, 64);
                pv += __shfl_xor(pv, 4, 64);
                pv += __shfl_xor(pv, 8, 64);
                if (ul == 0)
                    part[((size_t)(side*NCB + cid)*Bd + brow)*Sd + t] = pv;
            }
        }
    }
}

// ---------------- reduce attn partials ----------------
__global__ void k_attn(const float* __restrict__ part, const float* __restrict__ bml,
                       const float* __restrict__ bmr, float* __restrict__ attn) {
    int side = blockIdx.x >> 7;
    int b = blockIdx.x & 127;
    int t = threadIdx.x;
    float s = 0.f;
    for (int c = 0; c < NCB; ++c)
        s += part[((size_t)(side*NCB + c)*Bd + b)*Sd + t];
    float bias = side ? bmr[0] : bml[0];
    attn[(size_t)(side*Bd + b)*Sd + t] = sigm(s + bias) + 0.5f;
}

// ---------------- position weights + weighted memory + v_s ----------------
__global__ void k_wmem(const float* __restrict__ embed, const int* __restrict__ text,
                       const float* __restrict__ attn, const int* __restrict__ lens,
                       unsigned short* __restrict__ memw, float* __restrict__ vs) {
    int b = blockIdx.x;
    __shared__ float w_sh[Sd];
    __shared__ int text_s[Sd];
    int memlen = lens[b*4+0], asplen = lens[b*4+1], leftlen = lens[b*4+2];
    int a_start = leftlen - asplen, a_end = leftlen;
    const float* attl = attn + (size_t)b*Sd;
    const float* attr = attn + (size_t)(Bd + b)*Sd;
    if (threadIdx.x < Sd) {
        int i = threadIdx.x;
        int irr = a_end - 1 - i; irr = irr < 0 ? 0 : (irr > Sd-1 ? Sd-1 : irr);
        int ils = i - a_start;   ils = ils < 0 ? 0 : (ils > Sd-1 ? Sd-1 : ils);
        float arr_ = attr[irr], als = attl[ils];
        float w = (i < a_start) ? arr_ : ((i < a_end) ? 0.5f*(arr_+als) : als);
        if (i >= memlen) w = 1.0f;
        w_sh[i] = w;
        text_s[i] = text[b*Sd + i];
    }
    __syncthreads();
    int e = threadIdx.x;
    float acc = 0.f;
    float invm = 1.0f/(float)lens[b*4+0];
    for (int s = 0; s < Sd; ++s) {
        float v = (e < Ed) ? embed[(size_t)text_s[s]*Ed + e] : 0.f;
        float mw = v * w_sh[s];
        memw[((size_t)b*Sd + s)*EP + e] = f2bf(mw);
        acc += mw;
    }
    vs[b*EP + e] = acc * invm;
}

// ---------------- per-batch u = b1 + va@W1a^T + vs@W1s^T ----------------
__global__ void k_u(const float* __restrict__ w1, const float* __restrict__ b1,
                    const float* __restrict__ va, const float* __restrict__ vs,
                    float* __restrict__ u) {
    int b = blockIdx.x;
    __shared__ float va_s[Ed], vs_s[Ed];
    for (int k = threadIdx.x; k < Ed; k += blockDim.x) {
        va_s[k] = va[b*EP+k];
        vs_s[k] = vs[b*EP+k];
    }
    __syncthreads();
    int e = threadIdx.x;
    if (e >= EP) return;
    float acc = 0.f;
    if (e < Ed) {
        acc = b1[e];
        const float* r = w1 + (size_t)e*900;
        for (int k = 0; k < Ed; ++k) acc += va_s[k]*r[300+k];
        for (int k = 0; k < Ed; ++k) acc += vs_s[k]*r[600+k];
    }
    u[b*EP + e] = acc;
}

// ---------------- c[b,s] = w2 . tanh(memw@W1m^T + u)  (MFMA) ----------------
__global__ __launch_bounds__(256) void k_c(const unsigned short* __restrict__ memw,
                   const unsigned short* __restrict__ w1b,
                   const float* __restrict__ u, const float* __restrict__ w2,
                   float* __restrict__ cout) {
    int b = blockIdx.x >> 2;
    int s0 = (blockIdx.x & 3) * 64;
    __shared__ __align__(16) unsigned short A_s[64*328];
    __shared__ __align__(16) unsigned short Bp_s[EP*32];
    __shared__ float u_s[EP], w2_s[EP];
    for (int i = threadIdx.x; i < EP; i += 256) {
        u_s[i] = u[b*EP + i];
        w2_s[i] = (i < Ed) ? w2[i] : 0.f;
    }
    const unsigned short* Ag = memw + ((size_t)b*Sd + s0)*EP;
    for (int c8 = threadIdx.x; c8 < 64*40; c8 += 256) {
        int r = c8 / 40, kk = (c8 - r*40)*8;
        *(bfrag*)(A_s + r*328 + kk) = *(const bfrag*)(Ag + (size_t)r*EP + kk);
    }

    int wave = threadIdx.x >> 6, lane = threadIdx.x & 63;
    int ul = lane & 15, lq = lane >> 4;
    const f32x4 zero4 = {0.f,0.f,0.f,0.f};
    f32x4 acc[20];
    #pragma unroll
    for (int n = 0; n < 20; ++n) acc[n] = zero4;

    for (int kp = 0; kp < 10; ++kp) {
        __syncthreads();
        for (int c8 = threadIdx.x; c8 < EP*4; c8 += 256) {
            int e = c8 >> 2, kk = (c8 & 3)*8;
            *(bfrag*)(Bp_s + e*32 + kk) = *(const bfrag*)(w1b + (size_t)e*EP + kp*32 + kk);
        }
        __syncthreads();
        bfrag a = *(const bfrag*)(A_s + (wave*16 + ul)*328 + kp*32 + lq*8);
        #pragma unroll
        for (int n = 0; n < 20; ++n) {
            bfrag bb = *(const bfrag*)(Bp_s + (n*16 + ul)*32 + lq*8);
            acc[n] = __builtin_amdgcn_mfma_f32_16x16x32_bf16(a, bb, acc[n], 0, 0, 0);
        }
    }
    float cs[4] = {0.f,0.f,0.f,0.f};
    #pragma unroll
    for (int n = 0; n < 20; ++n) {
        int e = n*16 + ul;
        #pragma unroll
        for (int i = 0; i < 4; ++i)
            cs[i] += w2_s[e] * fast_tanh(acc[n][i] + u_s[e]);
    }
    #pragma unroll
    for (int i = 0; i < 4; ++i) {
        float v = cs[i];
        v += __shfl_xor(v, 1, 64); v += __shfl_xor(v, 2, 64);
        v += __shfl_xor(v, 4, 64); v += __shfl_xor(v, 8, 64);
        if (ul == 0) cout[(size_t)b*Sd + s0 + wave*16 + lq*4 + i] = v;
    }
}

// ---------------- softmax over s ----------------
__global__ void k_alpha(const float* __restrict__ cin, float* __restrict__ alpha) {
    int b = blockIdx.x;
    int t = threadIdx.x;
    __shared__ float buf[Sd];
    float v = cin[(size_t)b*Sd + t];
    buf[t] = v; __syncthreads();
    for (int s2 = 128; s2 > 0; s2 >>= 1) {
        if (t < s2) buf[t] = fmaxf(buf[t], buf[t+s2]);
        __syncthreads();
    }
    float mx = buf[0];
    __syncthreads();
    float ex = __expf(v - mx);
    buf[t] = ex; __syncthreads();
    for (int s2 = 128; s2 > 0; s2 >>= 1) {
        if (t < s2) buf[t] += buf[t+s2];
        __syncthreads();
    }
    alpha[(size_t)b*Sd + t] = ex / buf[0];
}

// ---------------- v_ts, v_ns, v_ms, logits, softmax ----------------
__global__ void k_final(const unsigned short* __restrict__ memw, const float* __restrict__ alpha,
                        const float* __restrict__ vs, const float* __restrict__ wm,
                        const float* __restrict__ bm, const float* __restrict__ wd,
                        const float* __restrict__ bd, float* __restrict__ out) {
    int b = blockIdx.x;
    __shared__ float al_s[Sd];
    __shared__ float vns_s[Ed];
    __shared__ float vms_s[Ed];
    __shared__ float lg_s[Pd];
    if (threadIdx.x < Sd) al_s[threadIdx.x] = alpha[(size_t)b*Sd + threadIdx.x];
    __syncthreads();
    int e = threadIdx.x;
    if (e < Ed) {
        float acc = 0.f;
        const unsigned short* mp = memw + (size_t)b*Sd*EP + e;
        for (int s = 0; s < Sd; ++s) acc += bf2f(mp[(size_t)s*EP]) * al_s[s];
        vns_s[e] = acc + vs[b*EP + e];
    }
    __syncthreads();
    if (e < Ed) {
        float acc = bm[e];
        const float* r = wm + (size_t)e*Ed;
        for (int k = 0; k < Ed; ++k) acc += vns_s[k]*r[k];
        vms_s[e] = fast_tanh(acc);
    }
    __syncthreads();
    if (e < Pd) {
        float acc = bd[e];
        const float* r = wd + (size_t)e*Ed;
        for (int k = 0; k < Ed; ++k) acc += vms_s[k]*r[k];
        lg_s[e] = acc;
    }
    __syncthreads();
    if (e < Pd) {
        float m = fmaxf(lg_s[0], fmaxf(lg_s[1], lg_s[2]));
        float den = __expf(lg_s[0]-m)+__expf(lg_s[1]-m)+__expf(lg_s[2]-m);
        out[b*Pd + e] = __expf(lg_s[e]-m)/den;
    }
}

extern "C" void kernel_launch(void* const* d_in, const int* in_sizes, int n_in,
                              void* d_out, int out_size, void* d_ws, size_t ws_size,
                              hipStream_t stream) {
    const float* embed = (const float*)d_in[0];
    const float* w1    = (const float*)d_in[1];
    const float* b1    = (const float*)d_in[2];
    const float* w2    = (const float*)d_in[3];
    const float* wm    = (const float*)d_in[4];
    const float* bm    = (const float*)d_in[5];
    const float* wd    = (const float*)d_in[6];
    const float* bd    = (const float*)d_in[7];
    const float* wih_l = (const float*)d_in[8];
    const float* whh_l = (const float*)d_in[9];
    const float* bih_l = (const float*)d_in[10];
    const float* bhh_l = (const float*)d_in[11];
    const float* wih_r = (const float*)d_in[12];
    const float* whh_r = (const float*)d_in[13];
    const float* bih_r = (const float*)d_in[14];
    const float* bhh_r = (const float*)d_in[15];
    const float* wml   = (const float*)d_in[16];
    const float* bml   = (const float*)d_in[17];
    const float* wmr   = (const float*)d_in[18];
    const float* bmr   = (const float*)d_in[19];
    const int* text    = (const int*)d_in[20];
    const int* aspect  = (const int*)d_in[21];
    const int* xl      = (const int*)d_in[22];
    const int* xr      = (const int*)d_in[23];

    if (ws_size < (size_t)WS_NEEDED) return;
    char* ws = (char*)d_ws;
    int* lens            = (int*)(ws + OFF_LENS);
    int* bars            = (int*)(ws + OFF_BARS);
    float* va            = (float*)(ws + OFF_VA);
    float* vs            = (float*)(ws + OFF_VS);
    float* u             = (float*)(ws + OFF_U);
    float* attn          = (float*)(ws + OFF_ATTN);
    float* alpha         = (float*)(ws + OFF_ALPHA);
    float* c             = (float*)(ws + OFF_C);
    unsigned short* hbuf = (unsigned short*)(ws + OFF_HBUF);
    float* part          = (float*)(ws + OFF_PART);
    unsigned short* w1b  = (unsigned short*)(ws + OFF_W1B);
    unsigned short* xemb = (unsigned short*)(ws + OFF_XEMB);
    unsigned short* memw = (unsigned short*)(ws + OFF_MEMW);

    hipMemsetAsync(ws + OFF_BARS, 0, 4096, stream);
    hipMemsetAsync(ws + OFF_HBUF, 0, 327680, stream);

    k_lengths<<<128, 256, 0, stream>>>(text, aspect, xl, lens);
    k_va     <<<128, 320, 0, stream>>>(embed, aspect, lens, va);
    k_xemb   <<<512, 256, 0, stream>>>(embed, xl, xr, xemb);
    k_w1conv <<<400, 256, 0, stream>>>(w1, w1b);
    k_gru    <<<GRID_GRU, 256, 0, stream>>>(wih_l, whh_l, bih_l, bhh_l,
                                            wih_r, whh_r, bih_r, bhh_r,
                                            wml, wmr, xemb, hbuf, part, bars);
    k_attn   <<<256, 256, 0, stream>>>(part, bml, bmr, attn);
    k_wmem   <<<128, 320, 0, stream>>>(embed, text, attn, lens, memw, vs);
    k_u      <<<128, 320, 0, stream>>>(w1, b1, va, vs, u);
    k_c      <<<512, 256, 0, stream>>>(memw, w1b, u, w2, c);
    k_alpha  <<<128, 256, 0, stream>>>(c, alpha);
    k_final  <<<128, 320, 0, stream>>>(memw, alpha, vs, wm, bm, wd, bd, (float*)d_out);
}